// Round 8
// baseline (668.959 us; speedup 1.0000x reference)
//
#include <hip/hip_runtime.h>
#include <math.h>

#define F 64
#define PR_ROWS 16  // rows per block in prop kernel (4 rows/wave)

using short8 = __attribute__((ext_vector_type(8))) short;
using f32x4  = __attribute__((ext_vector_type(4))) float;

static __device__ __forceinline__ ushort f2bf(float f) {
    uint u = __float_as_uint(f);
    uint r = (u + 0x7fffu + ((u >> 16) & 1u)) >> 16;  // RNE
    return (ushort)r;
}
static __device__ __forceinline__ float bf2f(ushort v) {
    return __uint_as_float(((uint)v) << 16);
}

// ---------- CSR build (rows padded to mult-8, column-only edges) ----------

__global__ __launch_bounds__(256) void deg_kernel(const int* __restrict__ ei, int E,
                                                  int* __restrict__ deg) {
    int e = blockIdx.x * 256 + threadIdx.x;
    if (e >= E) return;
    int r = ei[e], c = ei[E + e];
    if (r != c) atomicAdd(&deg[r], 1);
}

// scans PADDED degrees: pdeg = ceil(deg/8)*8
__global__ __launch_bounds__(256) void scan1_kernel(const int* __restrict__ deg,
                                                    int* __restrict__ rp,
                                                    int* __restrict__ bsum, int Nv) {
    __shared__ int sh[256];
    int t = threadIdx.x;
    int base = blockIdx.x * 1024 + t * 4;
    int v0 = (base + 0 < Nv) ? ((deg[base + 0] + 7) & ~7) : 0;
    int v1 = (base + 1 < Nv) ? ((deg[base + 1] + 7) & ~7) : 0;
    int v2 = (base + 2 < Nv) ? ((deg[base + 2] + 7) & ~7) : 0;
    int v3 = (base + 3 < Nv) ? ((deg[base + 3] + 7) & ~7) : 0;
    int s = v0 + v1 + v2 + v3;
    sh[t] = s;
    __syncthreads();
    for (int off = 1; off < 256; off <<= 1) {
        int a = (t >= off) ? sh[t - off] : 0;
        __syncthreads();
        sh[t] += a;
        __syncthreads();
    }
    int run = sh[t] - s;
    run += v0; if (base + 0 < Nv) rp[base + 1] = run;
    run += v1; if (base + 1 < Nv) rp[base + 2] = run;
    run += v2; if (base + 2 < Nv) rp[base + 3] = run;
    run += v3; if (base + 3 < Nv) rp[base + 4] = run;
    if (t == 255) bsum[blockIdx.x] = sh[255];
}

__global__ __launch_bounds__(256) void scan2_kernel(int* __restrict__ bsum, int nb) {
    __shared__ int sh[256];
    int t = threadIdx.x;
    int v = (t < nb) ? bsum[t] : 0;
    sh[t] = v;
    __syncthreads();
    for (int off = 1; off < 256; off <<= 1) {
        int a = (t >= off) ? sh[t - off] : 0;
        __syncthreads();
        sh[t] += a;
        __syncthreads();
    }
    if (t < nb) bsum[t] = sh[t] - v;
}

// scan3 + dinv fused
__global__ __launch_bounds__(256) void scan3_kernel(int* __restrict__ rp,
                                                    const int* __restrict__ bsum,
                                                    const int* __restrict__ deg,
                                                    float* __restrict__ dinv, int Nv) {
    int i = blockIdx.x * 256 + threadIdx.x;
    if (i == 0) rp[0] = 0;
    if (i < Nv) {
        rp[i + 1] += bsum[i >> 10];
        int d = deg[i];
        dinv[i] = d > 0 ? rsqrtf((float)d) : 0.f;
    }
}

// column-only scatter; dinv[c]==0 edges -> sentinel row Nv; the LAST arriving
// edge of each row pads the tail slots with the sentinel.
__global__ __launch_bounds__(256) void scatter_kernel(const int* __restrict__ ei, int E,
                                                      const int* __restrict__ rp,
                                                      int* __restrict__ fill,
                                                      const float* __restrict__ dinv,
                                                      const int* __restrict__ deg,
                                                      int* __restrict__ ce, int Nv) {
    int e = blockIdx.x * 256 + threadIdx.x;
    if (e >= E) return;
    int r = ei[e], c = ei[E + e];
    if (r == c) return;
    int old = atomicAdd(&fill[r], 1);
    ce[rp[r] + old] = (dinv[c] > 0.f) ? c : Nv;
    if (old == deg[r] - 1) {
        int q = rp[r] + deg[r], qe = rp[r + 1];
        for (; q < qe; q++) ce[q] = Nv;
    }
}

// ---------- init: G0 = bf16(sinv .* x) (+ sentinel row), WbT transpose ----------

__global__ __launch_bounds__(256) void init_kernel(const float4* __restrict__ src,
                                                   ushort4* __restrict__ dst,
                                                   const float* __restrict__ dinv,
                                                   const float* __restrict__ W,
                                                   ushort* __restrict__ WbT,
                                                   int n4, int KK, int Nv) {
    int i = blockIdx.x * 256 + threadIdx.x;
    if (i < 16) dst[(size_t)Nv * 16 + i] = make_ushort4(0, 0, 0, 0);  // row Nv = 0
    if (i < n4) {
        int row = i >> 4;
        float dr = dinv[row];
        float sv = dr > 0.f ? dr : 1.f;
        float4 v = src[i];
        dst[i] = make_ushort4(f2bf(sv * v.x), f2bf(sv * v.y),
                              f2bf(sv * v.z), f2bf(sv * v.w));
        return;
    }
    int t = i - n4;
    if (t < KK * F) {
        int col = t / KK, kk = t - col * KK;
        WbT[t] = f2bf(W[(size_t)kk * F + col]);
    }
}

// ---------- weightless prop: raw = -dinv_r * sum(G[c]); tk = 2*raw - tm2 ----------
// 16 gather chains per iteration (one latency round trip for the common
// padded-degree-16 row), 8-wide tail. bf16 G output LDS-staged, full-line stores.

__global__ __launch_bounds__(256, 4) void prop_v6(const ushort* __restrict__ Gsrc,
                                                  const float* __restrict__ Tm2,
                                                  float* __restrict__ Toutf,
                                                  ushort* __restrict__ Gout,
                                                  const int* __restrict__ rp,
                                                  const int* __restrict__ ce,
                                                  const float* __restrict__ dinv,
                                                  int Nv, int first, int store_f) {
    __shared__ __align__(16) ushort ush[PR_ROWS][F];
    int wave = threadIdx.x >> 6, lane = threadIdx.x & 63;
    int rbase = blockIdx.x * PR_ROWS + wave * 4;

    if (blockIdx.x == 0 && threadIdx.x < 8)  // zero sentinel row of Gout
        ((uint4*)(Gout + (size_t)Nv * F))[threadIdx.x] = make_uint4(0, 0, 0, 0);

    for (int r = 0; r < 4; r++) {
        int i = rbase + r;
        bool act = i < Nv;
        int ii = act ? i : 0;
        float dr = dinv[ii];
        float tm2 = first ? 0.f : Tm2[(size_t)ii * F + lane];  // prefetch early
        int s = rp[ii], e = rp[ii + 1];
        float a0 = 0.f, a1 = 0.f, a2 = 0.f, a3 = 0.f;
        float a4 = 0.f, a5 = 0.f, a6 = 0.f, a7 = 0.f;
        float a8 = 0.f, a9 = 0.f, aA = 0.f, aB = 0.f;
        float aC = 0.f, aD = 0.f, aE = 0.f, aF = 0.f;
        int p = s;
        for (; p + 16 <= e; p += 16) {  // 16 independent miss chains
            int4 q0 = *(const int4*)(ce + p);
            int4 q1 = *(const int4*)(ce + p + 4);
            int4 q2 = *(const int4*)(ce + p + 8);
            int4 q3 = *(const int4*)(ce + p + 12);
            a0 += bf2f(Gsrc[(size_t)q0.x * F + lane]);
            a1 += bf2f(Gsrc[(size_t)q0.y * F + lane]);
            a2 += bf2f(Gsrc[(size_t)q0.z * F + lane]);
            a3 += bf2f(Gsrc[(size_t)q0.w * F + lane]);
            a4 += bf2f(Gsrc[(size_t)q1.x * F + lane]);
            a5 += bf2f(Gsrc[(size_t)q1.y * F + lane]);
            a6 += bf2f(Gsrc[(size_t)q1.z * F + lane]);
            a7 += bf2f(Gsrc[(size_t)q1.w * F + lane]);
            a8 += bf2f(Gsrc[(size_t)q2.x * F + lane]);
            a9 += bf2f(Gsrc[(size_t)q2.y * F + lane]);
            aA += bf2f(Gsrc[(size_t)q2.z * F + lane]);
            aB += bf2f(Gsrc[(size_t)q2.w * F + lane]);
            aC += bf2f(Gsrc[(size_t)q3.x * F + lane]);
            aD += bf2f(Gsrc[(size_t)q3.y * F + lane]);
            aE += bf2f(Gsrc[(size_t)q3.z * F + lane]);
            aF += bf2f(Gsrc[(size_t)q3.w * F + lane]);
        }
        if (p < e) {  // exactly one 8-wide group remains (pad is mult-8)
            int4 q0 = *(const int4*)(ce + p);
            int4 q1 = *(const int4*)(ce + p + 4);
            a0 += bf2f(Gsrc[(size_t)q0.x * F + lane]);
            a1 += bf2f(Gsrc[(size_t)q0.y * F + lane]);
            a2 += bf2f(Gsrc[(size_t)q0.z * F + lane]);
            a3 += bf2f(Gsrc[(size_t)q0.w * F + lane]);
            a4 += bf2f(Gsrc[(size_t)q1.x * F + lane]);
            a5 += bf2f(Gsrc[(size_t)q1.y * F + lane]);
            a6 += bf2f(Gsrc[(size_t)q1.z * F + lane]);
            a7 += bf2f(Gsrc[(size_t)q1.w * F + lane]);
        }
        float sum = (((a0 + a1) + (a2 + a3)) + ((a4 + a5) + (a6 + a7)))
                  + (((a8 + a9) + (aA + aB)) + ((aC + aD) + (aE + aF)));
        float raw = -dr * sum;
        float tk = first ? raw : fmaf(2.f, raw, -tm2);
        if (act && store_f) Toutf[(size_t)i * F + lane] = tk;
        float sv = dr > 0.f ? dr : 1.f;
        ush[wave * 4 + r][lane] = f2bf(sv * tk);
    }
    __syncthreads();
    int t = threadIdx.x;
    if (t < 128) {  // 16 rows * 128B = 128 uint4 contiguous full lines
        int row = t >> 3;
        if (blockIdx.x * PR_ROWS + row < Nv)
            ((uint4*)Gout)[(size_t)blockIdx.x * 128 + t] = ((const uint4*)ush)[t];
    }
}

// ---------- MFMA GEMM over NSL slices (K = NSL*64) ----------
// Wave strip = 16 rows x 64 cols. A row r holds sinv_r*T; epilogue multiplies
// by s_r = sqrt(deg) (or 1), so out = sum_k T_k @ W_k. LAST fuses bias+LN+ELU.

template <int NSL, int FIRST, int LAST>
__global__ __launch_bounds__(256) void gemm_all(
    const ushort* __restrict__ g0, const ushort* __restrict__ g1,
    const ushort* __restrict__ g2, const ushort* __restrict__ g3,
    const ushort* __restrict__ g4, const ushort* __restrict__ g5,
    const ushort* __restrict__ g6, const ushort* __restrict__ g7,
    const ushort* __restrict__ WbT, int kkbase, int KK,
    float* __restrict__ out, const float* __restrict__ bias,
    const float* __restrict__ lnw, const float* __restrict__ lnb,
    const int* __restrict__ deg, int Nv) {
    const ushort* gs[8] = {g0, g1, g2, g3, g4, g5, g6, g7};
    int wave = threadIdx.x >> 6, lane = threadIdx.x & 63;
    int rbase = (blockIdx.x * 4 + wave) * 16;
    if (rbase >= Nv) return;
    int r15 = lane & 15, kg = lane >> 4;
    int arow = rbase + r15;
    if (arow >= Nv) arow = Nv - 1;  // clamp; clamped rows never stored

    f32x4 acc[4];
#pragma unroll
    for (int t = 0; t < 4; t++) acc[t] = (f32x4){0.f, 0.f, 0.f, 0.f};

#pragma unroll
    for (int st = 0; st < 2 * NSL; st++) {  // K-steps of 32
        const ushort* A = gs[st >> 1];
        short8 a = *(const short8*)(A + (size_t)arow * F + (st & 1) * 32 + kg * 8);
#pragma unroll
        for (int t = 0; t < 4; t++) {
            int col = t * 16 + r15;
            short8 b = *(const short8*)(WbT + (size_t)col * KK + kkbase + st * 32 + kg * 8);
            acc[t] = __builtin_amdgcn_mfma_f32_16x16x32_bf16(a, b, acc[t], 0, 0, 0);
        }
    }

    if (!LAST) {
#pragma unroll
        for (int t = 0; t < 4; t++) {
            int col = t * 16 + r15;
#pragma unroll
            for (int j = 0; j < 4; j++) {
                int row = rbase + kg * 4 + j;
                if (row < Nv) {
                    size_t idx = (size_t)row * F + col;
                    out[idx] = FIRST ? acc[t][j] : out[idx] + acc[t][j];
                }
            }
        }
    } else {
        float bc[4], wc[4], gc[4];
#pragma unroll
        for (int t = 0; t < 4; t++) {
            int col = t * 16 + r15;
            bc[t] = bias[col]; wc[t] = lnw[col]; gc[t] = lnb[col];
        }
#pragma unroll
        for (int j = 0; j < 4; j++) {
            int row = rbase + kg * 4 + j;
            int rr = row < Nv ? row : Nv - 1;  // whole 16-lane group uniform
            int dg = deg[rr];
            float sr = dg > 0 ? sqrtf((float)dg) : 1.f;  // undo sinv row scale
            float v[4];
            float s = 0.f;
#pragma unroll
            for (int t = 0; t < 4; t++) {
                int col = t * 16 + r15;
                float a_ = acc[t][j];
                if (!FIRST) a_ += out[(size_t)rr * F + col];
                v[t] = a_ * sr + bc[t];
                s += v[t];
            }
            s += __shfl_xor(s, 1, 64); s += __shfl_xor(s, 2, 64);
            s += __shfl_xor(s, 4, 64); s += __shfl_xor(s, 8, 64);
            float mu = s * (1.f / F);
            float q = 0.f;
#pragma unroll
            for (int t = 0; t < 4; t++) { float d = v[t] - mu; q += d * d; }
            q += __shfl_xor(q, 1, 64); q += __shfl_xor(q, 2, 64);
            q += __shfl_xor(q, 4, 64); q += __shfl_xor(q, 8, 64);
            float inv = rsqrtf(q * (1.f / F) + 1e-5f);
            if (row < Nv) {
#pragma unroll
                for (int t = 0; t < 4; t++) {
                    int col = t * 16 + r15;
                    float y = (v[t] - mu) * inv * wc[t] + gc[t];
                    out[(size_t)row * F + col] = y > 0.f ? y : expm1f(y);
                }
            }
        }
    }
}

// ---------- host ----------

extern "C" void kernel_launch(void* const* d_in, const int* in_sizes, int n_in,
                              void* d_out, int out_size, void* d_ws, size_t ws_size,
                              hipStream_t stream) {
    (void)n_in; (void)out_size;
    const float* x    = (const float*)d_in[0];
    const int*   ei   = (const int*)d_in[1];
    const float* W    = (const float*)d_in[2];
    const float* bias = (const float*)d_in[3];
    const float* lnw  = (const float*)d_in[4];
    const float* lnb  = (const float*)d_in[5];
    float* out = (float*)d_out;

    int Nv = in_sizes[0] / F;
    int E  = in_sizes[1] / 2;
    int K  = in_sizes[2] / (F * F);  // 8
    int KK = K * F;

    char* base = (char*)d_ws;
    size_t off = 0;
    auto alloc = [&](size_t b) -> void* {
        void* p = base + off;
        off += (b + 255) & ~(size_t)255;
        return p;
    };
    int*    degfill = (int*)alloc((size_t)2 * Nv * 4);  // deg | fill, one memset
    int*    deg  = degfill;
    int*    fill = degfill + Nv;
    int*    rp   = (int*)alloc(((size_t)Nv + 1) * 4);
    int     nb   = (Nv + 1023) / 1024;
    int*    bsum = (int*)alloc((size_t)nb * 4);
    float*  dinv = (float*)alloc((size_t)Nv * 4);
    int*    ce   = (int*)alloc(((size_t)E + 8 * Nv) * 4);  // padded CSR columns
    float*  Ta   = (float*)alloc((size_t)Nv * F * 4);      // T_k f32, k odd
    float*  Tb   = (float*)alloc((size_t)Nv * F * 4);      // T_k f32, k even
    ushort* WbT  = (ushort*)alloc((size_t)KK * F * 2);
    size_t fixed = off;

    size_t gbytes = ((size_t)Nv + 1) * F * 2;  // one bf16 slice incl. sentinel row
    size_t galign = (gbytes + 255) & ~(size_t)255;
    int full = (K == 8 && fixed + 8 * galign <= ws_size) ? 1 : 0;
    int nG = full ? 8 : 3;
    ushort* G[8];
    for (int i = 0; i < nG; i++) G[i] = (ushort*)alloc(gbytes);
    if (off > ws_size) return;

    hipMemsetAsync(degfill, 0, (size_t)2 * Nv * 4, stream);

    int gE = (E + 255) / 256, gN = (Nv + 255) / 256;
    deg_kernel<<<gE, 256, 0, stream>>>(ei, E, deg);
    scan1_kernel<<<nb, 256, 0, stream>>>(deg, rp, bsum, Nv);
    scan2_kernel<<<1, 256, 0, stream>>>(bsum, nb);
    scan3_kernel<<<gN, 256, 0, stream>>>(rp, bsum, deg, dinv, Nv);
    scatter_kernel<<<gE, 256, 0, stream>>>(ei, E, rp, fill, dinv, deg, ce, Nv);

    int n4 = (Nv * F) / 4;
    int initN = n4 + KK * F;
    init_kernel<<<(initN + 255) / 256, 256, 0, stream>>>((const float4*)x, (ushort4*)G[0],
                                                         dinv, W, WbT, n4, KK, Nv);

    int gP = (Nv + PR_ROWS - 1) / PR_ROWS;
    int gG = (Nv + 63) / 64;

    for (int k = 1; k < K; k++) {
        float* tof = (k & 1) ? Ta : Tb;
        const float* tm2 = (k < 2) ? nullptr : (k == 2 ? x : (const float*)tof);
        int store_f = (k <= K - 3) ? 1 : 0;
        const ushort* gsrc = full ? G[k - 1] : G[(k - 1) % 3];
        ushort*       gdst = full ? G[k]     : G[k % 3];
        prop_v6<<<gP, 256, 0, stream>>>(gsrc, tm2, tof, gdst, rp, ce, dinv,
                                        Nv, k == 1 ? 1 : 0, store_f);
        if (!full && (k & 1)) {  // pair rotation fallback
            int p = k >> 1;
            const ushort* a0 = G[(2 * p) % 3];
            const ushort* a1 = G[(2 * p + 1) % 3];
            if (p == 0)
                gemm_all<2, 1, 0><<<gG, 256, 0, stream>>>(a0, a1, 0, 0, 0, 0, 0, 0,
                    WbT, p * 128, KK, out, bias, lnw, lnb, deg, Nv);
            else if (k < K - 1)
                gemm_all<2, 0, 0><<<gG, 256, 0, stream>>>(a0, a1, 0, 0, 0, 0, 0, 0,
                    WbT, p * 128, KK, out, bias, lnw, lnb, deg, Nv);
            else
                gemm_all<2, 0, 1><<<gG, 256, 0, stream>>>(a0, a1, 0, 0, 0, 0, 0, 0,
                    WbT, p * 128, KK, out, bias, lnw, lnb, deg, Nv);
        }
    }
    if (full)
        gemm_all<8, 1, 1><<<gG, 256, 0, stream>>>(G[0], G[1], G[2], G[3],
                                                  G[4], G[5], G[6], G[7],
                                                  WbT, 0, KK, out, bias, lnw, lnb,
                                                  deg, Nv);
}

// Round 9
// 561.400 us; speedup vs baseline: 1.1916x; 1.1916x over previous
//
#include <hip/hip_runtime.h>
#include <math.h>

#define F 64
#define PR_ROWS 16  // rows per block in prop kernel (4 rows/wave)

using short8 = __attribute__((ext_vector_type(8))) short;
using f32x4  = __attribute__((ext_vector_type(4))) float;

static __device__ __forceinline__ ushort f2bf(float f) {
    uint u = __float_as_uint(f);
    uint r = (u + 0x7fffu + ((u >> 16) & 1u)) >> 16;  // RNE
    return (ushort)r;
}
static __device__ __forceinline__ float bf2f(ushort v) {
    return __uint_as_float(((uint)v) << 16);
}

// ---------- CSR build (rows padded to mult-8, column-only edges) ----------

__global__ __launch_bounds__(256) void deg_kernel(const int* __restrict__ ei, int E,
                                                  int* __restrict__ deg) {
    int e = blockIdx.x * 256 + threadIdx.x;
    if (e >= E) return;
    int r = ei[e], c = ei[E + e];
    if (r != c) atomicAdd(&deg[r], 1);
}

// scans PADDED degrees: pdeg = ceil(deg/8)*8
__global__ __launch_bounds__(256) void scan1_kernel(const int* __restrict__ deg,
                                                    int* __restrict__ rp,
                                                    int* __restrict__ bsum, int Nv) {
    __shared__ int sh[256];
    int t = threadIdx.x;
    int base = blockIdx.x * 1024 + t * 4;
    int v0 = (base + 0 < Nv) ? ((deg[base + 0] + 7) & ~7) : 0;
    int v1 = (base + 1 < Nv) ? ((deg[base + 1] + 7) & ~7) : 0;
    int v2 = (base + 2 < Nv) ? ((deg[base + 2] + 7) & ~7) : 0;
    int v3 = (base + 3 < Nv) ? ((deg[base + 3] + 7) & ~7) : 0;
    int s = v0 + v1 + v2 + v3;
    sh[t] = s;
    __syncthreads();
    for (int off = 1; off < 256; off <<= 1) {
        int a = (t >= off) ? sh[t - off] : 0;
        __syncthreads();
        sh[t] += a;
        __syncthreads();
    }
    int run = sh[t] - s;
    run += v0; if (base + 0 < Nv) rp[base + 1] = run;
    run += v1; if (base + 1 < Nv) rp[base + 2] = run;
    run += v2; if (base + 2 < Nv) rp[base + 3] = run;
    run += v3; if (base + 3 < Nv) rp[base + 4] = run;
    if (t == 255) bsum[blockIdx.x] = sh[255];
}

__global__ __launch_bounds__(256) void scan2_kernel(int* __restrict__ bsum, int nb) {
    __shared__ int sh[256];
    int t = threadIdx.x;
    int v = (t < nb) ? bsum[t] : 0;
    sh[t] = v;
    __syncthreads();
    for (int off = 1; off < 256; off <<= 1) {
        int a = (t >= off) ? sh[t - off] : 0;
        __syncthreads();
        sh[t] += a;
        __syncthreads();
    }
    if (t < nb) bsum[t] = sh[t] - v;
}

// scan3 + dinv fused
__global__ __launch_bounds__(256) void scan3_kernel(int* __restrict__ rp,
                                                    const int* __restrict__ bsum,
                                                    const int* __restrict__ deg,
                                                    float* __restrict__ dinv, int Nv) {
    int i = blockIdx.x * 256 + threadIdx.x;
    if (i == 0) rp[0] = 0;
    if (i < Nv) {
        rp[i + 1] += bsum[i >> 10];
        int d = deg[i];
        dinv[i] = d > 0 ? rsqrtf((float)d) : 0.f;
    }
}

// column-only scatter; dinv[c]==0 edges -> sentinel row Nv; the LAST arriving
// edge of each row pads the tail slots with the sentinel.
__global__ __launch_bounds__(256) void scatter_kernel(const int* __restrict__ ei, int E,
                                                      const int* __restrict__ rp,
                                                      int* __restrict__ fill,
                                                      const float* __restrict__ dinv,
                                                      const int* __restrict__ deg,
                                                      int* __restrict__ ce, int Nv) {
    int e = blockIdx.x * 256 + threadIdx.x;
    if (e >= E) return;
    int r = ei[e], c = ei[E + e];
    if (r == c) return;
    int old = atomicAdd(&fill[r], 1);
    ce[rp[r] + old] = (dinv[c] > 0.f) ? c : Nv;
    if (old == deg[r] - 1) {
        int q = rp[r] + deg[r], qe = rp[r + 1];
        for (; q < qe; q++) ce[q] = Nv;
    }
}

// ---------- init: G0 = bf16(sinv .* x) (+ sentinel row), WbT transpose ----------

__global__ __launch_bounds__(256) void init_kernel(const float4* __restrict__ src,
                                                   ushort4* __restrict__ dst,
                                                   const float* __restrict__ dinv,
                                                   const float* __restrict__ W,
                                                   ushort* __restrict__ WbT,
                                                   int n4, int KK, int Nv) {
    int i = blockIdx.x * 256 + threadIdx.x;
    if (i < 16) dst[(size_t)Nv * 16 + i] = make_ushort4(0, 0, 0, 0);  // row Nv = 0
    if (i < n4) {
        int row = i >> 4;
        float dr = dinv[row];
        float sv = dr > 0.f ? dr : 1.f;
        float4 v = src[i];
        dst[i] = make_ushort4(f2bf(sv * v.x), f2bf(sv * v.y),
                              f2bf(sv * v.z), f2bf(sv * v.w));
        return;
    }
    int t = i - n4;
    if (t < KK * F) {
        int col = t / KK, kk = t - col * KK;
        WbT[t] = f2bf(W[(size_t)kk * F + col]);
    }
}

// ---------- weightless prop, bf16-only state ----------
// raw = -dinv_r * sum(G_{k-1}[c]); tm2 = s_r * G_{k-2}[i]; tk = 2*raw - tm2;
// G_k[i] = bf16(sinv_r * tk). 8 gather chains (proven v5 structure); G output
// LDS-staged, full-line uint4 stores. No f32 T stream at all.

__global__ __launch_bounds__(256) void prop_v7(const ushort* __restrict__ Gsrc,
                                               const ushort* __restrict__ Gm2,
                                               ushort* __restrict__ Gout,
                                               const int* __restrict__ rp,
                                               const int* __restrict__ ce,
                                               const float* __restrict__ dinv,
                                               const int* __restrict__ deg,
                                               int Nv, int first) {
    __shared__ __align__(16) ushort ush[PR_ROWS][F];
    int wave = threadIdx.x >> 6, lane = threadIdx.x & 63;
    int rbase = blockIdx.x * PR_ROWS + wave * 4;

    if (blockIdx.x == 0 && threadIdx.x < 8)  // zero sentinel row of Gout
        ((uint4*)(Gout + (size_t)Nv * F))[threadIdx.x] = make_uint4(0, 0, 0, 0);

    for (int r = 0; r < 4; r++) {
        int i = rbase + r;
        bool act = i < Nv;
        int ii = act ? i : 0;
        float dr = dinv[ii];
        int dg = deg[ii];
        float sr = dg > 0 ? sqrtf((float)dg) : 1.f;   // 1/sinv
        float tm2 = first ? 0.f : sr * bf2f(Gm2[(size_t)ii * F + lane]);  // prefetch
        int s = rp[ii], e = rp[ii + 1];
        float s0 = 0.f, s1 = 0.f, s2 = 0.f, s3 = 0.f;
        float s4 = 0.f, s5 = 0.f, s6 = 0.f, s7 = 0.f;
        for (int p = s; p < e; p += 8) {  // 8 independent miss chains, no remainder
            int4 q0 = *(const int4*)(ce + p);
            int4 q1 = *(const int4*)(ce + p + 4);
            s0 += bf2f(Gsrc[(size_t)q0.x * F + lane]);
            s1 += bf2f(Gsrc[(size_t)q0.y * F + lane]);
            s2 += bf2f(Gsrc[(size_t)q0.z * F + lane]);
            s3 += bf2f(Gsrc[(size_t)q0.w * F + lane]);
            s4 += bf2f(Gsrc[(size_t)q1.x * F + lane]);
            s5 += bf2f(Gsrc[(size_t)q1.y * F + lane]);
            s6 += bf2f(Gsrc[(size_t)q1.z * F + lane]);
            s7 += bf2f(Gsrc[(size_t)q1.w * F + lane]);
        }
        float sum = ((s0 + s1) + (s2 + s3)) + ((s4 + s5) + (s6 + s7));
        float raw = -dr * sum;
        float tk = first ? raw : fmaf(2.f, raw, -tm2);
        float sv = dr > 0.f ? dr : 1.f;
        ush[wave * 4 + r][lane] = f2bf(sv * tk);
    }
    __syncthreads();
    int t = threadIdx.x;
    if (t < 128) {  // 16 rows * 128B = 128 uint4 contiguous full lines
        int row = t >> 3;
        if (blockIdx.x * PR_ROWS + row < Nv)
            ((uint4*)Gout)[(size_t)blockIdx.x * 128 + t] = ((const uint4*)ush)[t];
    }
}

// ---------- MFMA GEMM over NSL slices (K = NSL*64) ----------
// Wave strip = 16 rows x 64 cols. A row r holds sinv_r*T; epilogue multiplies
// by s_r = sqrt(deg) (or 1), so out = sum_k T_k @ W_k. LAST fuses bias+LN+ELU.

template <int NSL, int FIRST, int LAST>
__global__ __launch_bounds__(256) void gemm_all(
    const ushort* __restrict__ g0, const ushort* __restrict__ g1,
    const ushort* __restrict__ g2, const ushort* __restrict__ g3,
    const ushort* __restrict__ g4, const ushort* __restrict__ g5,
    const ushort* __restrict__ g6, const ushort* __restrict__ g7,
    const ushort* __restrict__ WbT, int kkbase, int KK,
    float* __restrict__ out, const float* __restrict__ bias,
    const float* __restrict__ lnw, const float* __restrict__ lnb,
    const int* __restrict__ deg, int Nv) {
    const ushort* gs[8] = {g0, g1, g2, g3, g4, g5, g6, g7};
    int wave = threadIdx.x >> 6, lane = threadIdx.x & 63;
    int rbase = (blockIdx.x * 4 + wave) * 16;
    if (rbase >= Nv) return;
    int r15 = lane & 15, kg = lane >> 4;
    int arow = rbase + r15;
    if (arow >= Nv) arow = Nv - 1;  // clamp; clamped rows never stored

    f32x4 acc[4];
#pragma unroll
    for (int t = 0; t < 4; t++) acc[t] = (f32x4){0.f, 0.f, 0.f, 0.f};

#pragma unroll
    for (int st = 0; st < 2 * NSL; st++) {  // K-steps of 32
        const ushort* A = gs[st >> 1];
        short8 a = *(const short8*)(A + (size_t)arow * F + (st & 1) * 32 + kg * 8);
#pragma unroll
        for (int t = 0; t < 4; t++) {
            int col = t * 16 + r15;
            short8 b = *(const short8*)(WbT + (size_t)col * KK + kkbase + st * 32 + kg * 8);
            acc[t] = __builtin_amdgcn_mfma_f32_16x16x32_bf16(a, b, acc[t], 0, 0, 0);
        }
    }

    if (!LAST) {
#pragma unroll
        for (int t = 0; t < 4; t++) {
            int col = t * 16 + r15;
#pragma unroll
            for (int j = 0; j < 4; j++) {
                int row = rbase + kg * 4 + j;
                if (row < Nv) {
                    size_t idx = (size_t)row * F + col;
                    out[idx] = FIRST ? acc[t][j] : out[idx] + acc[t][j];
                }
            }
        }
    } else {
        float bc[4], wc[4], gc[4];
#pragma unroll
        for (int t = 0; t < 4; t++) {
            int col = t * 16 + r15;
            bc[t] = bias[col]; wc[t] = lnw[col]; gc[t] = lnb[col];
        }
#pragma unroll
        for (int j = 0; j < 4; j++) {
            int row = rbase + kg * 4 + j;
            int rr = row < Nv ? row : Nv - 1;  // whole 16-lane group uniform
            int dg = deg[rr];
            float sr = dg > 0 ? sqrtf((float)dg) : 1.f;  // undo sinv row scale
            float v[4];
            float s = 0.f;
#pragma unroll
            for (int t = 0; t < 4; t++) {
                int col = t * 16 + r15;
                float a_ = acc[t][j];
                if (!FIRST) a_ += out[(size_t)rr * F + col];
                v[t] = a_ * sr + bc[t];
                s += v[t];
            }
            s += __shfl_xor(s, 1, 64); s += __shfl_xor(s, 2, 64);
            s += __shfl_xor(s, 4, 64); s += __shfl_xor(s, 8, 64);
            float mu = s * (1.f / F);
            float q = 0.f;
#pragma unroll
            for (int t = 0; t < 4; t++) { float d = v[t] - mu; q += d * d; }
            q += __shfl_xor(q, 1, 64); q += __shfl_xor(q, 2, 64);
            q += __shfl_xor(q, 4, 64); q += __shfl_xor(q, 8, 64);
            float inv = rsqrtf(q * (1.f / F) + 1e-5f);
            if (row < Nv) {
#pragma unroll
                for (int t = 0; t < 4; t++) {
                    int col = t * 16 + r15;
                    float y = (v[t] - mu) * inv * wc[t] + gc[t];
                    out[(size_t)row * F + col] = y > 0.f ? y : expm1f(y);
                }
            }
        }
    }
}

// ---------- host ----------

extern "C" void kernel_launch(void* const* d_in, const int* in_sizes, int n_in,
                              void* d_out, int out_size, void* d_ws, size_t ws_size,
                              hipStream_t stream) {
    (void)n_in; (void)out_size;
    const float* x    = (const float*)d_in[0];
    const int*   ei   = (const int*)d_in[1];
    const float* W    = (const float*)d_in[2];
    const float* bias = (const float*)d_in[3];
    const float* lnw  = (const float*)d_in[4];
    const float* lnb  = (const float*)d_in[5];
    float* out = (float*)d_out;

    int Nv = in_sizes[0] / F;
    int E  = in_sizes[1] / 2;
    int K  = in_sizes[2] / (F * F);  // 8
    int KK = K * F;

    char* base = (char*)d_ws;
    size_t off = 0;
    auto alloc = [&](size_t b) -> void* {
        void* p = base + off;
        off += (b + 255) & ~(size_t)255;
        return p;
    };
    int*    degfill = (int*)alloc((size_t)2 * Nv * 4);  // deg | fill, one memset
    int*    deg  = degfill;
    int*    fill = degfill + Nv;
    int*    rp   = (int*)alloc(((size_t)Nv + 1) * 4);
    int     nb   = (Nv + 1023) / 1024;
    int*    bsum = (int*)alloc((size_t)nb * 4);
    float*  dinv = (float*)alloc((size_t)Nv * 4);
    int*    ce   = (int*)alloc(((size_t)E + 8 * Nv) * 4);  // padded CSR columns
    ushort* WbT  = (ushort*)alloc((size_t)KK * F * 2);
    size_t fixed = off;

    size_t gbytes = ((size_t)Nv + 1) * F * 2;  // one bf16 slice incl. sentinel row
    size_t galign = (gbytes + 255) & ~(size_t)255;
    int full = (K == 8 && fixed + 8 * galign <= ws_size) ? 1 : 0;
    int nG = full ? 8 : 3;
    ushort* G[8];
    for (int i = 0; i < nG; i++) G[i] = (ushort*)alloc(gbytes);
    if (off > ws_size) return;

    hipMemsetAsync(degfill, 0, (size_t)2 * Nv * 4, stream);

    int gE = (E + 255) / 256, gN = (Nv + 255) / 256;
    deg_kernel<<<gE, 256, 0, stream>>>(ei, E, deg);
    scan1_kernel<<<nb, 256, 0, stream>>>(deg, rp, bsum, Nv);
    scan2_kernel<<<1, 256, 0, stream>>>(bsum, nb);
    scan3_kernel<<<gN, 256, 0, stream>>>(rp, bsum, deg, dinv, Nv);
    scatter_kernel<<<gE, 256, 0, stream>>>(ei, E, rp, fill, dinv, deg, ce, Nv);

    int n4 = (Nv * F) / 4;
    int initN = n4 + KK * F;
    init_kernel<<<(initN + 255) / 256, 256, 0, stream>>>((const float4*)x, (ushort4*)G[0],
                                                         dinv, W, WbT, n4, KK, Nv);

    int gP = (Nv + PR_ROWS - 1) / PR_ROWS;
    int gG = (Nv + 63) / 64;

    for (int k = 1; k < K; k++) {
        const ushort* gsrc = full ? G[k - 1] : G[(k - 1) % 3];
        const ushort* gm2  = (k < 2) ? (const ushort*)nullptr
                                     : (full ? G[k - 2] : G[(k - 2) % 3]);
        ushort*       gdst = full ? G[k] : G[k % 3];
        prop_v7<<<gP, 256, 0, stream>>>(gsrc, gm2, gdst, rp, ce, dinv, deg,
                                        Nv, k == 1 ? 1 : 0);
        if (!full && (k & 1)) {  // pair rotation fallback
            int p = k >> 1;
            const ushort* a0 = G[(2 * p) % 3];
            const ushort* a1 = G[(2 * p + 1) % 3];
            if (p == 0)
                gemm_all<2, 1, 0><<<gG, 256, 0, stream>>>(a0, a1, 0, 0, 0, 0, 0, 0,
                    WbT, p * 128, KK, out, bias, lnw, lnb, deg, Nv);
            else if (k < K - 1)
                gemm_all<2, 0, 0><<<gG, 256, 0, stream>>>(a0, a1, 0, 0, 0, 0, 0, 0,
                    WbT, p * 128, KK, out, bias, lnw, lnb, deg, Nv);
            else
                gemm_all<2, 0, 1><<<gG, 256, 0, stream>>>(a0, a1, 0, 0, 0, 0, 0, 0,
                    WbT, p * 128, KK, out, bias, lnw, lnb, deg, Nv);
        }
    }
    if (full)
        gemm_all<8, 1, 1><<<gG, 256, 0, stream>>>(G[0], G[1], G[2], G[3],
                                                  G[4], G[5], G[6], G[7],
                                                  WbT, 0, KK, out, bias, lnw, lnb,
                                                  deg, Nv);
}

// Round 10
// 561.387 us; speedup vs baseline: 1.1916x; 1.0000x over previous
//
#include <hip/hip_runtime.h>
#include <math.h>

#define F 64
#define PR_ROWS 16  // rows per block in prop kernel (4 rows/wave)

using short8 = __attribute__((ext_vector_type(8))) short;
using f32x4  = __attribute__((ext_vector_type(4))) float;

static __device__ __forceinline__ ushort f2bf(float f) {
    uint u = __float_as_uint(f);
    uint r = (u + 0x7fffu + ((u >> 16) & 1u)) >> 16;  // RNE
    return (ushort)r;
}
static __device__ __forceinline__ float bf2f(ushort v) {
    return __uint_as_float(((uint)v) << 16);
}

// row -> XCD group (any deterministic 8-way partition works)
static __device__ __forceinline__ int rgroup(int r, float invg) {
    int g = (int)((float)r * invg);
    return g > 7 ? 7 : g;
}

// ---------- CSR build (rows padded to mult-8, column-only edges) ----------
// deg + scatter are XCD-localized: blocks assigned round-robin to XCDs
// (blockIdx % 8); each handles only rows of its group so the random
// atomics/writes for a given row stay in ONE per-XCD L2 (sector RMW
// accumulates while resident -> ~1 writeback per sector instead of ~8-16).

__global__ __launch_bounds__(256) void deg_kernel(const int* __restrict__ ei, int E,
                                                  int* __restrict__ deg, float invg) {
    int xcd = blockIdx.x & 7;
    int e = (blockIdx.x >> 3) * 256 + threadIdx.x;
    if (e >= E) return;
    int r = ei[e], c = ei[E + e];
    if (r == c) return;
    if (rgroup(r, invg) != xcd) return;
    atomicAdd(&deg[r], 1);
}

// scans PADDED degrees: pdeg = ceil(deg/8)*8
__global__ __launch_bounds__(256) void scan1_kernel(const int* __restrict__ deg,
                                                    int* __restrict__ rp,
                                                    int* __restrict__ bsum, int Nv) {
    __shared__ int sh[256];
    int t = threadIdx.x;
    int base = blockIdx.x * 1024 + t * 4;
    int v0 = (base + 0 < Nv) ? ((deg[base + 0] + 7) & ~7) : 0;
    int v1 = (base + 1 < Nv) ? ((deg[base + 1] + 7) & ~7) : 0;
    int v2 = (base + 2 < Nv) ? ((deg[base + 2] + 7) & ~7) : 0;
    int v3 = (base + 3 < Nv) ? ((deg[base + 3] + 7) & ~7) : 0;
    int s = v0 + v1 + v2 + v3;
    sh[t] = s;
    __syncthreads();
    for (int off = 1; off < 256; off <<= 1) {
        int a = (t >= off) ? sh[t - off] : 0;
        __syncthreads();
        sh[t] += a;
        __syncthreads();
    }
    int run = sh[t] - s;
    run += v0; if (base + 0 < Nv) rp[base + 1] = run;
    run += v1; if (base + 1 < Nv) rp[base + 2] = run;
    run += v2; if (base + 2 < Nv) rp[base + 3] = run;
    run += v3; if (base + 3 < Nv) rp[base + 4] = run;
    if (t == 255) bsum[blockIdx.x] = sh[255];
}

__global__ __launch_bounds__(256) void scan2_kernel(int* __restrict__ bsum, int nb) {
    __shared__ int sh[256];
    int t = threadIdx.x;
    int v = (t < nb) ? bsum[t] : 0;
    sh[t] = v;
    __syncthreads();
    for (int off = 1; off < 256; off <<= 1) {
        int a = (t >= off) ? sh[t - off] : 0;
        __syncthreads();
        sh[t] += a;
        __syncthreads();
    }
    if (t < nb) bsum[t] = sh[t] - v;
}

// scan3 + dinv fused
__global__ __launch_bounds__(256) void scan3_kernel(int* __restrict__ rp,
                                                    const int* __restrict__ bsum,
                                                    const int* __restrict__ deg,
                                                    float* __restrict__ dinv, int Nv) {
    int i = blockIdx.x * 256 + threadIdx.x;
    if (i == 0) rp[0] = 0;
    if (i < Nv) {
        rp[i + 1] += bsum[i >> 10];
        int d = deg[i];
        dinv[i] = d > 0 ? rsqrtf((float)d) : 0.f;
    }
}

// XCD-localized column-only scatter; dinv[c]==0 edges -> sentinel row Nv;
// the LAST arriving edge of each row pads the tail slots with the sentinel.
__global__ __launch_bounds__(256) void scatter_kernel(const int* __restrict__ ei, int E,
                                                      const int* __restrict__ rp,
                                                      int* __restrict__ fill,
                                                      const float* __restrict__ dinv,
                                                      const int* __restrict__ deg,
                                                      int* __restrict__ ce, int Nv,
                                                      float invg) {
    int xcd = blockIdx.x & 7;
    int e = (blockIdx.x >> 3) * 256 + threadIdx.x;
    if (e >= E) return;
    int r = ei[e], c = ei[E + e];
    if (r == c) return;
    if (rgroup(r, invg) != xcd) return;
    int old = atomicAdd(&fill[r], 1);
    ce[rp[r] + old] = (dinv[c] > 0.f) ? c : Nv;
    if (old == deg[r] - 1) {
        int q = rp[r] + deg[r], qe = rp[r + 1];
        for (; q < qe; q++) ce[q] = Nv;
    }
}

// ---------- init: G0 = bf16(sinv .* x) (+ sentinel row), WbT transpose ----------

__global__ __launch_bounds__(256) void init_kernel(const float4* __restrict__ src,
                                                   ushort4* __restrict__ dst,
                                                   const float* __restrict__ dinv,
                                                   const float* __restrict__ W,
                                                   ushort* __restrict__ WbT,
                                                   int n4, int KK, int Nv) {
    int i = blockIdx.x * 256 + threadIdx.x;
    if (i < 16) dst[(size_t)Nv * 16 + i] = make_ushort4(0, 0, 0, 0);  // row Nv = 0
    if (i < n4) {
        int row = i >> 4;
        float dr = dinv[row];
        float sv = dr > 0.f ? dr : 1.f;
        float4 v = src[i];
        dst[i] = make_ushort4(f2bf(sv * v.x), f2bf(sv * v.y),
                              f2bf(sv * v.z), f2bf(sv * v.w));
        return;
    }
    int t = i - n4;
    if (t < KK * F) {
        int col = t / KK, kk = t - col * KK;
        WbT[t] = f2bf(W[(size_t)kk * F + col]);
    }
}

// ---------- weightless prop, bf16-only state ----------
// raw = -dinv_r * sum(G_{k-1}[c]); tm2 = s_r * G_{k-2}[i]; tk = 2*raw - tm2;
// G_k[i] = bf16(sinv_r * tk). 8 gather chains; G output LDS-staged,
// full-line uint4 stores. No f32 T stream.

__global__ __launch_bounds__(256) void prop_v7(const ushort* __restrict__ Gsrc,
                                               const ushort* __restrict__ Gm2,
                                               ushort* __restrict__ Gout,
                                               const int* __restrict__ rp,
                                               const int* __restrict__ ce,
                                               const float* __restrict__ dinv,
                                               const int* __restrict__ deg,
                                               int Nv, int first) {
    __shared__ __align__(16) ushort ush[PR_ROWS][F];
    int wave = threadIdx.x >> 6, lane = threadIdx.x & 63;
    int rbase = blockIdx.x * PR_ROWS + wave * 4;

    if (blockIdx.x == 0 && threadIdx.x < 8)  // zero sentinel row of Gout
        ((uint4*)(Gout + (size_t)Nv * F))[threadIdx.x] = make_uint4(0, 0, 0, 0);

    for (int r = 0; r < 4; r++) {
        int i = rbase + r;
        bool act = i < Nv;
        int ii = act ? i : 0;
        float dr = dinv[ii];
        int dg = deg[ii];
        float sr = dg > 0 ? sqrtf((float)dg) : 1.f;   // 1/sinv
        float tm2 = first ? 0.f : sr * bf2f(Gm2[(size_t)ii * F + lane]);  // prefetch
        int s = rp[ii], e = rp[ii + 1];
        float s0 = 0.f, s1 = 0.f, s2 = 0.f, s3 = 0.f;
        float s4 = 0.f, s5 = 0.f, s6 = 0.f, s7 = 0.f;
        for (int p = s; p < e; p += 8) {  // 8 independent miss chains, no remainder
            int4 q0 = *(const int4*)(ce + p);
            int4 q1 = *(const int4*)(ce + p + 4);
            s0 += bf2f(Gsrc[(size_t)q0.x * F + lane]);
            s1 += bf2f(Gsrc[(size_t)q0.y * F + lane]);
            s2 += bf2f(Gsrc[(size_t)q0.z * F + lane]);
            s3 += bf2f(Gsrc[(size_t)q0.w * F + lane]);
            s4 += bf2f(Gsrc[(size_t)q1.x * F + lane]);
            s5 += bf2f(Gsrc[(size_t)q1.y * F + lane]);
            s6 += bf2f(Gsrc[(size_t)q1.z * F + lane]);
            s7 += bf2f(Gsrc[(size_t)q1.w * F + lane]);
        }
        float sum = ((s0 + s1) + (s2 + s3)) + ((s4 + s5) + (s6 + s7));
        float raw = -dr * sum;
        float tk = first ? raw : fmaf(2.f, raw, -tm2);
        float sv = dr > 0.f ? dr : 1.f;
        ush[wave * 4 + r][lane] = f2bf(sv * tk);
    }
    __syncthreads();
    int t = threadIdx.x;
    if (t < 128) {  // 16 rows * 128B = 128 uint4 contiguous full lines
        int row = t >> 3;
        if (blockIdx.x * PR_ROWS + row < Nv)
            ((uint4*)Gout)[(size_t)blockIdx.x * 128 + t] = ((const uint4*)ush)[t];
    }
}

// ---------- MFMA GEMM over NSL slices (K = NSL*64) ----------

template <int NSL, int FIRST, int LAST>
__global__ __launch_bounds__(256) void gemm_all(
    const ushort* __restrict__ g0, const ushort* __restrict__ g1,
    const ushort* __restrict__ g2, const ushort* __restrict__ g3,
    const ushort* __restrict__ g4, const ushort* __restrict__ g5,
    const ushort* __restrict__ g6, const ushort* __restrict__ g7,
    const ushort* __restrict__ WbT, int kkbase, int KK,
    float* __restrict__ out, const float* __restrict__ bias,
    const float* __restrict__ lnw, const float* __restrict__ lnb,
    const int* __restrict__ deg, int Nv) {
    const ushort* gs[8] = {g0, g1, g2, g3, g4, g5, g6, g7};
    int wave = threadIdx.x >> 6, lane = threadIdx.x & 63;
    int rbase = (blockIdx.x * 4 + wave) * 16;
    if (rbase >= Nv) return;
    int r15 = lane & 15, kg = lane >> 4;
    int arow = rbase + r15;
    if (arow >= Nv) arow = Nv - 1;  // clamp; clamped rows never stored

    f32x4 acc[4];
#pragma unroll
    for (int t = 0; t < 4; t++) acc[t] = (f32x4){0.f, 0.f, 0.f, 0.f};

#pragma unroll
    for (int st = 0; st < 2 * NSL; st++) {  // K-steps of 32
        const ushort* A = gs[st >> 1];
        short8 a = *(const short8*)(A + (size_t)arow * F + (st & 1) * 32 + kg * 8);
#pragma unroll
        for (int t = 0; t < 4; t++) {
            int col = t * 16 + r15;
            short8 b = *(const short8*)(WbT + (size_t)col * KK + kkbase + st * 32 + kg * 8);
            acc[t] = __builtin_amdgcn_mfma_f32_16x16x32_bf16(a, b, acc[t], 0, 0, 0);
        }
    }

    if (!LAST) {
#pragma unroll
        for (int t = 0; t < 4; t++) {
            int col = t * 16 + r15;
#pragma unroll
            for (int j = 0; j < 4; j++) {
                int row = rbase + kg * 4 + j;
                if (row < Nv) {
                    size_t idx = (size_t)row * F + col;
                    out[idx] = FIRST ? acc[t][j] : out[idx] + acc[t][j];
                }
            }
        }
    } else {
        float bc[4], wc[4], gc[4];
#pragma unroll
        for (int t = 0; t < 4; t++) {
            int col = t * 16 + r15;
            bc[t] = bias[col]; wc[t] = lnw[col]; gc[t] = lnb[col];
        }
#pragma unroll
        for (int j = 0; j < 4; j++) {
            int row = rbase + kg * 4 + j;
            int rr = row < Nv ? row : Nv - 1;  // whole 16-lane group uniform
            int dg = deg[rr];
            float sr = dg > 0 ? sqrtf((float)dg) : 1.f;  // undo sinv row scale
            float v[4];
            float s = 0.f;
#pragma unroll
            for (int t = 0; t < 4; t++) {
                int col = t * 16 + r15;
                float a_ = acc[t][j];
                if (!FIRST) a_ += out[(size_t)rr * F + col];
                v[t] = a_ * sr + bc[t];
                s += v[t];
            }
            s += __shfl_xor(s, 1, 64); s += __shfl_xor(s, 2, 64);
            s += __shfl_xor(s, 4, 64); s += __shfl_xor(s, 8, 64);
            float mu = s * (1.f / F);
            float q = 0.f;
#pragma unroll
            for (int t = 0; t < 4; t++) { float d = v[t] - mu; q += d * d; }
            q += __shfl_xor(q, 1, 64); q += __shfl_xor(q, 2, 64);
            q += __shfl_xor(q, 4, 64); q += __shfl_xor(q, 8, 64);
            float inv = rsqrtf(q * (1.f / F) + 1e-5f);
            if (row < Nv) {
#pragma unroll
                for (int t = 0; t < 4; t++) {
                    int col = t * 16 + r15;
                    float y = (v[t] - mu) * inv * wc[t] + gc[t];
                    out[(size_t)row * F + col] = y > 0.f ? y : expm1f(y);
                }
            }
        }
    }
}

// ---------- host ----------

extern "C" void kernel_launch(void* const* d_in, const int* in_sizes, int n_in,
                              void* d_out, int out_size, void* d_ws, size_t ws_size,
                              hipStream_t stream) {
    (void)n_in; (void)out_size;
    const float* x    = (const float*)d_in[0];
    const int*   ei   = (const int*)d_in[1];
    const float* W    = (const float*)d_in[2];
    const float* bias = (const float*)d_in[3];
    const float* lnw  = (const float*)d_in[4];
    const float* lnb  = (const float*)d_in[5];
    float* out = (float*)d_out;

    int Nv = in_sizes[0] / F;
    int E  = in_sizes[1] / 2;
    int K  = in_sizes[2] / (F * F);  // 8
    int KK = K * F;
    float invg = 8.0f / (float)Nv;

    char* base = (char*)d_ws;
    size_t off = 0;
    auto alloc = [&](size_t b) -> void* {
        void* p = base + off;
        off += (b + 255) & ~(size_t)255;
        return p;
    };
    int*    degfill = (int*)alloc((size_t)2 * Nv * 4);  // deg | fill, one memset
    int*    deg  = degfill;
    int*    fill = degfill + Nv;
    int*    rp   = (int*)alloc(((size_t)Nv + 1) * 4);
    int     nb   = (Nv + 1023) / 1024;
    int*    bsum = (int*)alloc((size_t)nb * 4);
    float*  dinv = (float*)alloc((size_t)Nv * 4);
    int*    ce   = (int*)alloc(((size_t)E + 8 * Nv) * 4);  // padded CSR columns
    ushort* WbT  = (ushort*)alloc((size_t)KK * F * 2);
    size_t fixed = off;

    size_t gbytes = ((size_t)Nv + 1) * F * 2;  // one bf16 slice incl. sentinel row
    size_t galign = (gbytes + 255) & ~(size_t)255;
    int full = (K == 8 && fixed + 8 * galign <= ws_size) ? 1 : 0;
    int nG = full ? 8 : 3;
    ushort* G[8];
    for (int i = 0; i < nG; i++) G[i] = (ushort*)alloc(gbytes);
    if (off > ws_size) return;

    hipMemsetAsync(degfill, 0, (size_t)2 * Nv * 4, stream);

    int gE = (E + 255) / 256, gN = (Nv + 255) / 256;
    deg_kernel<<<8 * gE, 256, 0, stream>>>(ei, E, deg, invg);
    scan1_kernel<<<nb, 256, 0, stream>>>(deg, rp, bsum, Nv);
    scan2_kernel<<<1, 256, 0, stream>>>(bsum, nb);
    scan3_kernel<<<gN, 256, 0, stream>>>(rp, bsum, deg, dinv, Nv);
    scatter_kernel<<<8 * gE, 256, 0, stream>>>(ei, E, rp, fill, dinv, deg, ce, Nv, invg);

    int n4 = (Nv * F) / 4;
    int initN = n4 + KK * F;
    init_kernel<<<(initN + 255) / 256, 256, 0, stream>>>((const float4*)x, (ushort4*)G[0],
                                                         dinv, W, WbT, n4, KK, Nv);

    int gP = (Nv + PR_ROWS - 1) / PR_ROWS;
    int gG = (Nv + 63) / 64;

    for (int k = 1; k < K; k++) {
        const ushort* gsrc = full ? G[k - 1] : G[(k - 1) % 3];
        const ushort* gm2  = (k < 2) ? (const ushort*)nullptr
                                     : (full ? G[k - 2] : G[(k - 2) % 3]);
        ushort*       gdst = full ? G[k] : G[k % 3];
        prop_v7<<<gP, 256, 0, stream>>>(gsrc, gm2, gdst, rp, ce, dinv, deg,
                                        Nv, k == 1 ? 1 : 0);
        if (!full && (k & 1)) {  // pair rotation fallback
            int p = k >> 1;
            const ushort* a0 = G[(2 * p) % 3];
            const ushort* a1 = G[(2 * p + 1) % 3];
            if (p == 0)
                gemm_all<2, 1, 0><<<gG, 256, 0, stream>>>(a0, a1, 0, 0, 0, 0, 0, 0,
                    WbT, p * 128, KK, out, bias, lnw, lnb, deg, Nv);
            else if (k < K - 1)
                gemm_all<2, 0, 0><<<gG, 256, 0, stream>>>(a0, a1, 0, 0, 0, 0, 0, 0,
                    WbT, p * 128, KK, out, bias, lnw, lnb, deg, Nv);
            else
                gemm_all<2, 0, 1><<<gG, 256, 0, stream>>>(a0, a1, 0, 0, 0, 0, 0, 0,
                    WbT, p * 128, KK, out, bias, lnw, lnb, deg, Nv);
        }
    }
    if (full)
        gemm_all<8, 1, 1><<<gG, 256, 0, stream>>>(G[0], G[1], G[2], G[3],
                                                  G[4], G[5], G[6], G[7],
                                                  WbT, 0, KK, out, bias, lnw, lnb,
                                                  deg, Nv);
}

// Round 11
// 523.528 us; speedup vs baseline: 1.2778x; 1.0723x over previous
//
#include <hip/hip_runtime.h>
#include <math.h>

#define F 64
#define PR_ROWS 16  // rows per block in prop kernel (4 rows/wave)

using short8 = __attribute__((ext_vector_type(8))) short;
using f32x4  = __attribute__((ext_vector_type(4))) float;

static __device__ __forceinline__ ushort f2bf(float f) {
    uint u = __float_as_uint(f);
    uint r = (u + 0x7fffu + ((u >> 16) & 1u)) >> 16;  // RNE
    return (ushort)r;
}
static __device__ __forceinline__ float bf2f(ushort v) {
    return __uint_as_float(((uint)v) << 16);
}

// row -> XCD group
static __device__ __forceinline__ int rgroup(int r, float invg) {
    int g = (int)((float)r * invg);
    return g > 7 ? 7 : g;
}

// ---------- CSR build (rows padded to mult-8, column-only edges) ----------

__global__ __launch_bounds__(256) void deg_kernel(const int* __restrict__ ei, int E,
                                                  int* __restrict__ deg, float invg) {
    int xcd = blockIdx.x & 7;
    int e = (blockIdx.x >> 3) * 256 + threadIdx.x;
    if (e >= E) return;
    int r = ei[e], c = ei[E + e];
    if (r == c) return;
    if (rgroup(r, invg) != xcd) return;
    atomicAdd(&deg[r], 1);
}

// scans PADDED degrees: pdeg = ceil(deg/8)*8
__global__ __launch_bounds__(256) void scan1_kernel(const int* __restrict__ deg,
                                                    int* __restrict__ rp,
                                                    int* __restrict__ bsum, int Nv) {
    __shared__ int sh[256];
    int t = threadIdx.x;
    int base = blockIdx.x * 1024 + t * 4;
    int v0 = (base + 0 < Nv) ? ((deg[base + 0] + 7) & ~7) : 0;
    int v1 = (base + 1 < Nv) ? ((deg[base + 1] + 7) & ~7) : 0;
    int v2 = (base + 2 < Nv) ? ((deg[base + 2] + 7) & ~7) : 0;
    int v3 = (base + 3 < Nv) ? ((deg[base + 3] + 7) & ~7) : 0;
    int s = v0 + v1 + v2 + v3;
    sh[t] = s;
    __syncthreads();
    for (int off = 1; off < 256; off <<= 1) {
        int a = (t >= off) ? sh[t - off] : 0;
        __syncthreads();
        sh[t] += a;
        __syncthreads();
    }
    int run = sh[t] - s;
    run += v0; if (base + 0 < Nv) rp[base + 1] = run;
    run += v1; if (base + 1 < Nv) rp[base + 2] = run;
    run += v2; if (base + 2 < Nv) rp[base + 3] = run;
    run += v3; if (base + 3 < Nv) rp[base + 4] = run;
    if (t == 255) bsum[blockIdx.x] = sh[255];
}

__global__ __launch_bounds__(256) void scan2_kernel(int* __restrict__ bsum, int nb) {
    __shared__ int sh[256];
    int t = threadIdx.x;
    int v = (t < nb) ? bsum[t] : 0;
    sh[t] = v;
    __syncthreads();
    for (int off = 1; off < 256; off <<= 1) {
        int a = (t >= off) ? sh[t - off] : 0;
        __syncthreads();
        sh[t] += a;
        __syncthreads();
    }
    if (t < nb) bsum[t] = sh[t] - v;
}

// scan3 + dinv fused
__global__ __launch_bounds__(256) void scan3_kernel(int* __restrict__ rp,
                                                    const int* __restrict__ bsum,
                                                    const int* __restrict__ deg,
                                                    float* __restrict__ dinv, int Nv) {
    int i = blockIdx.x * 256 + threadIdx.x;
    if (i == 0) rp[0] = 0;
    if (i < Nv) {
        rp[i + 1] += bsum[i >> 10];
        int d = deg[i];
        dinv[i] = d > 0 ? rsqrtf((float)d) : 0.f;
    }
}

__global__ __launch_bounds__(256) void scatter_kernel(const int* __restrict__ ei, int E,
                                                      const int* __restrict__ rp,
                                                      int* __restrict__ fill,
                                                      const float* __restrict__ dinv,
                                                      const int* __restrict__ deg,
                                                      int* __restrict__ ce, int Nv,
                                                      float invg) {
    int xcd = blockIdx.x & 7;
    int e = (blockIdx.x >> 3) * 256 + threadIdx.x;
    if (e >= E) return;
    int r = ei[e], c = ei[E + e];
    if (r == c) return;
    if (rgroup(r, invg) != xcd) return;
    int old = atomicAdd(&fill[r], 1);
    ce[rp[r] + old] = (dinv[c] > 0.f) ? c : Nv;
    if (old == deg[r] - 1) {
        int q = rp[r] + deg[r], qe = rp[r + 1];
        for (; q < qe; q++) ce[q] = Nv;
    }
}

// ---------- init: G0 = bf16(sinv .* x), WbT transpose, WF fragment-major ----------
// WF layout: WF[((st*4 + t)*64 + lane)*8 + j] = bf16(W[kk][col]),
//   col = t*16 + (lane&15), kk = st*32 + (lane>>4)*8 + j  (st = 0..2K-1)
// -> gemm B-load is one contiguous 1KB access per wave per (st,t).

__global__ __launch_bounds__(256) void init_kernel(const float4* __restrict__ src,
                                                   ushort4* __restrict__ dst,
                                                   const float* __restrict__ dinv,
                                                   const float* __restrict__ W,
                                                   ushort* __restrict__ WbT,
                                                   ushort* __restrict__ WF,
                                                   int n4, int KK, int Nv) {
    int i = blockIdx.x * 256 + threadIdx.x;
    if (i < 16) dst[(size_t)Nv * 16 + i] = make_ushort4(0, 0, 0, 0);  // row Nv = 0
    if (i < n4) {
        int row = i >> 4;
        float dr = dinv[row];
        float sv = dr > 0.f ? dr : 1.f;
        float4 v = src[i];
        dst[i] = make_ushort4(f2bf(sv * v.x), f2bf(sv * v.y),
                              f2bf(sv * v.z), f2bf(sv * v.w));
        return;
    }
    int t = i - n4;
    if (t < KK * F) {  // WbT (pair-gemm fallback path)
        int col = t / KK, kk = t - col * KK;
        WbT[t] = f2bf(W[(size_t)kk * F + col]);
        return;
    }
    int u = t - KK * F;
    if (u < KK * F) {  // WF (fragment-major for gemm_full)
        int j = u & 7, lane = (u >> 3) & 63, tt = (u >> 9) & 3, st = u >> 11;
        int col = tt * 16 + (lane & 15);
        int kk = st * 32 + ((lane >> 4) << 3) + j;
        WF[u] = f2bf(W[(size_t)kk * F + col]);
    }
}

// ---------- weightless prop, bf16-only state (proven v7) ----------

__global__ __launch_bounds__(256) void prop_v7(const ushort* __restrict__ Gsrc,
                                               const ushort* __restrict__ Gm2,
                                               ushort* __restrict__ Gout,
                                               const int* __restrict__ rp,
                                               const int* __restrict__ ce,
                                               const float* __restrict__ dinv,
                                               const int* __restrict__ deg,
                                               int Nv, int first) {
    __shared__ __align__(16) ushort ush[PR_ROWS][F];
    int wave = threadIdx.x >> 6, lane = threadIdx.x & 63;
    int rbase = blockIdx.x * PR_ROWS + wave * 4;

    if (blockIdx.x == 0 && threadIdx.x < 8)  // zero sentinel row of Gout
        ((uint4*)(Gout + (size_t)Nv * F))[threadIdx.x] = make_uint4(0, 0, 0, 0);

    for (int r = 0; r < 4; r++) {
        int i = rbase + r;
        bool act = i < Nv;
        int ii = act ? i : 0;
        float dr = dinv[ii];
        int dg = deg[ii];
        float sr = dg > 0 ? sqrtf((float)dg) : 1.f;   // 1/sinv
        float tm2 = first ? 0.f : sr * bf2f(Gm2[(size_t)ii * F + lane]);  // prefetch
        int s = rp[ii], e = rp[ii + 1];
        float s0 = 0.f, s1 = 0.f, s2 = 0.f, s3 = 0.f;
        float s4 = 0.f, s5 = 0.f, s6 = 0.f, s7 = 0.f;
        for (int p = s; p < e; p += 8) {  // 8 independent miss chains, no remainder
            int4 q0 = *(const int4*)(ce + p);
            int4 q1 = *(const int4*)(ce + p + 4);
            s0 += bf2f(Gsrc[(size_t)q0.x * F + lane]);
            s1 += bf2f(Gsrc[(size_t)q0.y * F + lane]);
            s2 += bf2f(Gsrc[(size_t)q0.z * F + lane]);
            s3 += bf2f(Gsrc[(size_t)q0.w * F + lane]);
            s4 += bf2f(Gsrc[(size_t)q1.x * F + lane]);
            s5 += bf2f(Gsrc[(size_t)q1.y * F + lane]);
            s6 += bf2f(Gsrc[(size_t)q1.z * F + lane]);
            s7 += bf2f(Gsrc[(size_t)q1.w * F + lane]);
        }
        float sum = ((s0 + s1) + (s2 + s3)) + ((s4 + s5) + (s6 + s7));
        float raw = -dr * sum;
        float tk = first ? raw : fmaf(2.f, raw, -tm2);
        float sv = dr > 0.f ? dr : 1.f;
        ush[wave * 4 + r][lane] = f2bf(sv * tk);
    }
    __syncthreads();
    int t = threadIdx.x;
    if (t < 128) {  // 16 rows * 128B = 128 uint4 contiguous full lines
        int row = t >> 3;
        if (blockIdx.x * PR_ROWS + row < Nv)
            ((uint4*)Gout)[(size_t)blockIdx.x * 128 + t] = ((const uint4*)ush)[t];
    }
}

// ---------- gemm_full: out = ELU(LN(sr * sum_k T~_k @ W_k + bias)) ----------
// Block = 64 rows, K=512 in two LDS-staged chunks of 4 slices (32 KB).
// A staged with coalesced uint4 loads + XOR chunk swizzle (c ^= r&7):
// 16-lane strided read becomes 2-way bank aliasing (free, m136).
// B from WF fragment-major: contiguous 1KB per wave per (st,t).

__global__ __launch_bounds__(256) void gemm_full(
    const ushort* __restrict__ g0, const ushort* __restrict__ g1,
    const ushort* __restrict__ g2, const ushort* __restrict__ g3,
    const ushort* __restrict__ g4, const ushort* __restrict__ g5,
    const ushort* __restrict__ g6, const ushort* __restrict__ g7,
    const ushort* __restrict__ WF,
    float* __restrict__ out, const float* __restrict__ bias,
    const float* __restrict__ lnw, const float* __restrict__ lnb,
    const int* __restrict__ deg, int Nv) {
    __shared__ __align__(16) ushort A_lds[4 * 64 * 64];  // 32 KB
    uint4* Au4 = (uint4*)A_lds;
    int wave = threadIdx.x >> 6, lane = threadIdx.x & 63;
    int rbase64 = blockIdx.x * 64;
    if (rbase64 >= Nv) return;
    int rbase = rbase64 + wave * 16;
    int r15 = lane & 15, kg = lane >> 4;

    f32x4 acc[4];
#pragma unroll
    for (int t = 0; t < 4; t++) acc[t] = (f32x4){0.f, 0.f, 0.f, 0.f};

    // stage 4 slices (explicit pointers: no dynamic pointer-array indexing)
#define STAGE4(pA, pB, pC, pD)                                                  \
    {                                                                           \
        const ushort* ps_[4] = {pA, pB, pC, pD};                                \
        _Pragma("unroll")                                                       \
        for (int s4_ = 0; s4_ < 4; s4_++) {                                     \
            const ushort* A_ = ps_[s4_];                                        \
            _Pragma("unroll")                                                   \
            for (int it_ = 0; it_ < 2; it_++) {                                 \
                int lin_ = it_ * 256 + threadIdx.x;                             \
                int r_ = lin_ >> 3, c_ = lin_ & 7;                              \
                int grow_ = rbase64 + r_;                                       \
                if (grow_ > Nv) grow_ = Nv; /* sentinel zeros */                \
                uint4 v_ = *(const uint4*)(A_ + (size_t)grow_ * F + c_ * 8);    \
                Au4[(s4_ * 64 + r_) * 8 + (c_ ^ (r_ & 7))] = v_;                \
            }                                                                   \
        }                                                                       \
    }

    STAGE4(g0, g1, g2, g3);
    __syncthreads();
#pragma unroll
    for (int st8 = 0; st8 < 8; st8++) {        // slices 0..3
        int s4 = st8 >> 1, half = st8 & 1;
        int cidx = (half * 4 + kg) ^ (r15 & 7);
        short8 a = *(const short8*)&A_lds[((s4 * 64 + wave * 16 + r15) * 8 + cidx) * 8];
#pragma unroll
        for (int t = 0; t < 4; t++) {
            short8 b = *(const short8*)(WF + (((size_t)st8 * 4 + t) * 64 + lane) * 8);
            acc[t] = __builtin_amdgcn_mfma_f32_16x16x32_bf16(a, b, acc[t], 0, 0, 0);
        }
    }
    __syncthreads();
    STAGE4(g4, g5, g6, g7);
    __syncthreads();
#pragma unroll
    for (int st8 = 0; st8 < 8; st8++) {        // slices 4..7
        int s4 = st8 >> 1, half = st8 & 1;
        int cidx = (half * 4 + kg) ^ (r15 & 7);
        short8 a = *(const short8*)&A_lds[((s4 * 64 + wave * 16 + r15) * 8 + cidx) * 8];
#pragma unroll
        for (int t = 0; t < 4; t++) {
            short8 b = *(const short8*)(WF + (((size_t)(st8 + 8) * 4 + t) * 64 + lane) * 8);
            acc[t] = __builtin_amdgcn_mfma_f32_16x16x32_bf16(a, b, acc[t], 0, 0, 0);
        }
    }
#undef STAGE4

    // epilogue: row scale + bias + LayerNorm (16-lane group reduce) + ELU
    float bc[4], wc[4], gc[4];
#pragma unroll
    for (int t = 0; t < 4; t++) {
        int col = t * 16 + r15;
        bc[t] = bias[col]; wc[t] = lnw[col]; gc[t] = lnb[col];
    }
#pragma unroll
    for (int j = 0; j < 4; j++) {
        int row = rbase + kg * 4 + j;
        int rr = row < Nv ? row : Nv - 1;  // whole 16-lane group uniform
        int dg = deg[rr];
        float sr = dg > 0 ? sqrtf((float)dg) : 1.f;  // undo sinv row scale
        float v[4];
        float s = 0.f;
#pragma unroll
        for (int t = 0; t < 4; t++) {
            v[t] = acc[t][j] * sr + bc[t];
            s += v[t];
        }
        s += __shfl_xor(s, 1, 64); s += __shfl_xor(s, 2, 64);
        s += __shfl_xor(s, 4, 64); s += __shfl_xor(s, 8, 64);
        float mu = s * (1.f / F);
        float q = 0.f;
#pragma unroll
        for (int t = 0; t < 4; t++) { float d = v[t] - mu; q += d * d; }
        q += __shfl_xor(q, 1, 64); q += __shfl_xor(q, 2, 64);
        q += __shfl_xor(q, 4, 64); q += __shfl_xor(q, 8, 64);
        float inv = rsqrtf(q * (1.f / F) + 1e-5f);
        if (row < Nv) {
#pragma unroll
            for (int t = 0; t < 4; t++) {
                int col = t * 16 + r15;
                float y = (v[t] - mu) * inv * wc[t] + gc[t];
                out[(size_t)row * F + col] = y > 0.f ? y : expm1f(y);
            }
        }
    }
}

// ---------- pair-GEMM fallback (only if workspace too small for 8 slices) ----------

template <int NSL, int FIRST, int LAST>
__global__ __launch_bounds__(256) void gemm_all(
    const ushort* __restrict__ g0, const ushort* __restrict__ g1,
    const ushort* __restrict__ g2, const ushort* __restrict__ g3,
    const ushort* __restrict__ g4, const ushort* __restrict__ g5,
    const ushort* __restrict__ g6, const ushort* __restrict__ g7,
    const ushort* __restrict__ WbT, int kkbase, int KK,
    float* __restrict__ out, const float* __restrict__ bias,
    const float* __restrict__ lnw, const float* __restrict__ lnb,
    const int* __restrict__ deg, int Nv) {
    const ushort* gs[8] = {g0, g1, g2, g3, g4, g5, g6, g7};
    int wave = threadIdx.x >> 6, lane = threadIdx.x & 63;
    int rbase = (blockIdx.x * 4 + wave) * 16;
    if (rbase >= Nv) return;
    int r15 = lane & 15, kg = lane >> 4;
    int arow = rbase + r15;
    if (arow >= Nv) arow = Nv - 1;

    f32x4 acc[4];
#pragma unroll
    for (int t = 0; t < 4; t++) acc[t] = (f32x4){0.f, 0.f, 0.f, 0.f};

#pragma unroll
    for (int st = 0; st < 2 * NSL; st++) {
        const ushort* A = gs[st >> 1];
        short8 a = *(const short8*)(A + (size_t)arow * F + (st & 1) * 32 + kg * 8);
#pragma unroll
        for (int t = 0; t < 4; t++) {
            int col = t * 16 + r15;
            short8 b = *(const short8*)(WbT + (size_t)col * KK + kkbase + st * 32 + kg * 8);
            acc[t] = __builtin_amdgcn_mfma_f32_16x16x32_bf16(a, b, acc[t], 0, 0, 0);
        }
    }

    if (!LAST) {
#pragma unroll
        for (int t = 0; t < 4; t++) {
            int col = t * 16 + r15;
#pragma unroll
            for (int j = 0; j < 4; j++) {
                int row = rbase + kg * 4 + j;
                if (row < Nv) {
                    size_t idx = (size_t)row * F + col;
                    out[idx] = FIRST ? acc[t][j] : out[idx] + acc[t][j];
                }
            }
        }
    } else {
        float bc[4], wc[4], gc[4];
#pragma unroll
        for (int t = 0; t < 4; t++) {
            int col = t * 16 + r15;
            bc[t] = bias[col]; wc[t] = lnw[col]; gc[t] = lnb[col];
        }
#pragma unroll
        for (int j = 0; j < 4; j++) {
            int row = rbase + kg * 4 + j;
            int rr = row < Nv ? row : Nv - 1;
            int dg = deg[rr];
            float sr = dg > 0 ? sqrtf((float)dg) : 1.f;
            float v[4];
            float s = 0.f;
#pragma unroll
            for (int t = 0; t < 4; t++) {
                int col = t * 16 + r15;
                float a_ = acc[t][j];
                if (!FIRST) a_ += out[(size_t)rr * F + col];
                v[t] = a_ * sr + bc[t];
                s += v[t];
            }
            s += __shfl_xor(s, 1, 64); s += __shfl_xor(s, 2, 64);
            s += __shfl_xor(s, 4, 64); s += __shfl_xor(s, 8, 64);
            float mu = s * (1.f / F);
            float q = 0.f;
#pragma unroll
            for (int t = 0; t < 4; t++) { float d = v[t] - mu; q += d * d; }
            q += __shfl_xor(q, 1, 64); q += __shfl_xor(q, 2, 64);
            q += __shfl_xor(q, 4, 64); q += __shfl_xor(q, 8, 64);
            float inv = rsqrtf(q * (1.f / F) + 1e-5f);
            if (row < Nv) {
#pragma unroll
                for (int t = 0; t < 4; t++) {
                    int col = t * 16 + r15;
                    float y = (v[t] - mu) * inv * wc[t] + gc[t];
                    out[(size_t)row * F + col] = y > 0.f ? y : expm1f(y);
                }
            }
        }
    }
}

// ---------- host ----------

extern "C" void kernel_launch(void* const* d_in, const int* in_sizes, int n_in,
                              void* d_out, int out_size, void* d_ws, size_t ws_size,
                              hipStream_t stream) {
    (void)n_in; (void)out_size;
    const float* x    = (const float*)d_in[0];
    const int*   ei   = (const int*)d_in[1];
    const float* W    = (const float*)d_in[2];
    const float* bias = (const float*)d_in[3];
    const float* lnw  = (const float*)d_in[4];
    const float* lnb  = (const float*)d_in[5];
    float* out = (float*)d_out;

    int Nv = in_sizes[0] / F;
    int E  = in_sizes[1] / 2;
    int K  = in_sizes[2] / (F * F);  // 8
    int KK = K * F;
    float invg = 8.0f / (float)Nv;

    char* base = (char*)d_ws;
    size_t off = 0;
    auto alloc = [&](size_t b) -> void* {
        void* p = base + off;
        off += (b + 255) & ~(size_t)255;
        return p;
    };
    int*    degfill = (int*)alloc((size_t)2 * Nv * 4);  // deg | fill, one memset
    int*    deg  = degfill;
    int*    fill = degfill + Nv;
    int*    rp   = (int*)alloc(((size_t)Nv + 1) * 4);
    int     nb   = (Nv + 1023) / 1024;
    int*    bsum = (int*)alloc((size_t)nb * 4);
    float*  dinv = (float*)alloc((size_t)Nv * 4);
    int*    ce   = (int*)alloc(((size_t)E + 8 * Nv) * 4);  // padded CSR columns
    ushort* WbT  = (ushort*)alloc((size_t)KK * F * 2);
    ushort* WF   = (ushort*)alloc((size_t)KK * F * 2);
    size_t fixed = off;

    size_t gbytes = ((size_t)Nv + 1) * F * 2;  // one bf16 slice incl. sentinel row
    size_t galign = (gbytes + 255) & ~(size_t)255;
    int full = (K == 8 && fixed + 8 * galign <= ws_size) ? 1 : 0;
    int nG = full ? 8 : 3;
    ushort* G[8];
    for (int i = 0; i < nG; i++) G[i] = (ushort*)alloc(gbytes);
    if (off > ws_size) return;

    hipMemsetAsync(degfill, 0, (size_t)2 * Nv * 4, stream);

    int gE = (E + 255) / 256, gN = (Nv + 255) / 256;
    deg_kernel<<<8 * gE, 256, 0, stream>>>(ei, E, deg, invg);
    scan1_kernel<<<nb, 256, 0, stream>>>(deg, rp, bsum, Nv);
    scan2_kernel<<<1, 256, 0, stream>>>(bsum, nb);
    scan3_kernel<<<gN, 256, 0, stream>>>(rp, bsum, deg, dinv, Nv);
    scatter_kernel<<<8 * gE, 256, 0, stream>>>(ei, E, rp, fill, dinv, deg, ce, Nv, invg);

    int n4 = (Nv * F) / 4;
    int initN = n4 + 2 * KK * F;
    init_kernel<<<(initN + 255) / 256, 256, 0, stream>>>((const float4*)x, (ushort4*)G[0],
                                                         dinv, W, WbT, WF, n4, KK, Nv);

    int gP = (Nv + PR_ROWS - 1) / PR_ROWS;
    int gG = (Nv + 63) / 64;

    for (int k = 1; k < K; k++) {
        const ushort* gsrc = full ? G[k - 1] : G[(k - 1) % 3];
        const ushort* gm2  = (k < 2) ? (const ushort*)nullptr
                                     : (full ? G[k - 2] : G[(k - 2) % 3]);
        ushort*       gdst = full ? G[k] : G[k % 3];
        prop_v7<<<gP, 256, 0, stream>>>(gsrc, gm2, gdst, rp, ce, dinv, deg,
                                        Nv, k == 1 ? 1 : 0);
        if (!full && (k & 1)) {  // pair rotation fallback
            int p = k >> 1;
            const ushort* a0 = G[(2 * p) % 3];
            const ushort* a1 = G[(2 * p + 1) % 3];
            if (p == 0)
                gemm_all<2, 1, 0><<<gG, 256, 0, stream>>>(a0, a1, 0, 0, 0, 0, 0, 0,
                    WbT, p * 128, KK, out, bias, lnw, lnb, deg, Nv);
            else if (k < K - 1)
                gemm_all<2, 0, 0><<<gG, 256, 0, stream>>>(a0, a1, 0, 0, 0, 0, 0, 0,
                    WbT, p * 128, KK, out, bias, lnw, lnb, deg, Nv);
            else
                gemm_all<2, 0, 1><<<gG, 256, 0, stream>>>(a0, a1, 0, 0, 0, 0, 0, 0,
                    WbT, p * 128, KK, out, bias, lnw, lnb, deg, Nv);
        }
    }
    if (full)
        gemm_full<<<gG, 256, 0, stream>>>(G[0], G[1], G[2], G[3],
                                          G[4], G[5], G[6], G[7],
                                          WF, out, bias, lnw, lnb, deg, Nv);
}

// Round 12
// 489.393 us; speedup vs baseline: 1.3669x; 1.0697x over previous
//
#include <hip/hip_runtime.h>
#include <math.h>

#define F 64
#define PR_ROWS 16  // rows per block in prop kernel (4 rows/wave)

using short8 = __attribute__((ext_vector_type(8))) short;
using f32x4  = __attribute__((ext_vector_type(4))) float;

static __device__ __forceinline__ ushort f2bf(float f) {
    uint u = __float_as_uint(f);
    uint r = (u + 0x7fffu + ((u >> 16) & 1u)) >> 16;  // RNE
    return (ushort)r;
}
static __device__ __forceinline__ float bf2f(ushort v) {
    return __uint_as_float(((uint)v) << 16);
}

// row -> XCD group
static __device__ __forceinline__ int rgroup(int r, float invg) {
    int g = (int)((float)r * invg);
    return g > 7 ? 7 : g;
}

// ---------- CSR build (rows padded to mult-8, column-only edges) ----------

__global__ __launch_bounds__(256) void deg_kernel(const int* __restrict__ ei, int E,
                                                  int* __restrict__ deg, float invg) {
    int xcd = blockIdx.x & 7;
    int e = (blockIdx.x >> 3) * 256 + threadIdx.x;
    if (e >= E) return;
    int r = ei[e], c = ei[E + e];
    if (r == c) return;
    if (rgroup(r, invg) != xcd) return;
    atomicAdd(&deg[r], 1);
}

// scans PADDED degrees: pdeg = ceil(deg/8)*8
__global__ __launch_bounds__(256) void scan1_kernel(const int* __restrict__ deg,
                                                    int* __restrict__ rp,
                                                    int* __restrict__ bsum, int Nv) {
    __shared__ int sh[256];
    int t = threadIdx.x;
    int base = blockIdx.x * 1024 + t * 4;
    int v0 = (base + 0 < Nv) ? ((deg[base + 0] + 7) & ~7) : 0;
    int v1 = (base + 1 < Nv) ? ((deg[base + 1] + 7) & ~7) : 0;
    int v2 = (base + 2 < Nv) ? ((deg[base + 2] + 7) & ~7) : 0;
    int v3 = (base + 3 < Nv) ? ((deg[base + 3] + 7) & ~7) : 0;
    int s = v0 + v1 + v2 + v3;
    sh[t] = s;
    __syncthreads();
    for (int off = 1; off < 256; off <<= 1) {
        int a = (t >= off) ? sh[t - off] : 0;
        __syncthreads();
        sh[t] += a;
        __syncthreads();
    }
    int run = sh[t] - s;
    run += v0; if (base + 0 < Nv) rp[base + 1] = run;
    run += v1; if (base + 1 < Nv) rp[base + 2] = run;
    run += v2; if (base + 2 < Nv) rp[base + 3] = run;
    run += v3; if (base + 3 < Nv) rp[base + 4] = run;
    if (t == 255) bsum[blockIdx.x] = sh[255];
}

__global__ __launch_bounds__(256) void scan2_kernel(int* __restrict__ bsum, int nb) {
    __shared__ int sh[256];
    int t = threadIdx.x;
    int v = (t < nb) ? bsum[t] : 0;
    sh[t] = v;
    __syncthreads();
    for (int off = 1; off < 256; off <<= 1) {
        int a = (t >= off) ? sh[t - off] : 0;
        __syncthreads();
        sh[t] += a;
        __syncthreads();
    }
    if (t < nb) bsum[t] = sh[t] - v;
}

// scan3 + dinv fused
__global__ __launch_bounds__(256) void scan3_kernel(int* __restrict__ rp,
                                                    const int* __restrict__ bsum,
                                                    const int* __restrict__ deg,
                                                    float* __restrict__ dinv, int Nv) {
    int i = blockIdx.x * 256 + threadIdx.x;
    if (i == 0) rp[0] = 0;
    if (i < Nv) {
        rp[i + 1] += bsum[i >> 10];
        int d = deg[i];
        dinv[i] = d > 0 ? rsqrtf((float)d) : 0.f;
    }
}

__global__ __launch_bounds__(256) void scatter_kernel(const int* __restrict__ ei, int E,
                                                      const int* __restrict__ rp,
                                                      int* __restrict__ fill,
                                                      const float* __restrict__ dinv,
                                                      const int* __restrict__ deg,
                                                      int* __restrict__ ce, int Nv,
                                                      float invg) {
    int xcd = blockIdx.x & 7;
    int e = (blockIdx.x >> 3) * 256 + threadIdx.x;
    if (e >= E) return;
    int r = ei[e], c = ei[E + e];
    if (r == c) return;
    if (rgroup(r, invg) != xcd) return;
    int old = atomicAdd(&fill[r], 1);
    ce[rp[r] + old] = (dinv[c] > 0.f) ? c : Nv;
    if (old == deg[r] - 1) {
        int q = rp[r] + deg[r], qe = rp[r + 1];
        for (; q < qe; q++) ce[q] = Nv;
    }
}

// ---------- init: G0 = bf16(sinv .* x), WbT transpose, WF fragment-major ----------

__global__ __launch_bounds__(256) void init_kernel(const float4* __restrict__ src,
                                                   ushort4* __restrict__ dst,
                                                   const float* __restrict__ dinv,
                                                   const float* __restrict__ W,
                                                   ushort* __restrict__ WbT,
                                                   ushort* __restrict__ WF,
                                                   int n4, int KK, int Nv) {
    int i = blockIdx.x * 256 + threadIdx.x;
    if (i < 16) dst[(size_t)Nv * 16 + i] = make_ushort4(0, 0, 0, 0);  // row Nv = 0
    if (i < n4) {
        int row = i >> 4;
        float dr = dinv[row];
        float sv = dr > 0.f ? dr : 1.f;
        float4 v = src[i];
        dst[i] = make_ushort4(f2bf(sv * v.x), f2bf(sv * v.y),
                              f2bf(sv * v.z), f2bf(sv * v.w));
        return;
    }
    int t = i - n4;
    if (t < KK * F) {  // WbT (pair-gemm fallback path)
        int col = t / KK, kk = t - col * KK;
        WbT[t] = f2bf(W[(size_t)kk * F + col]);
        return;
    }
    int u = t - KK * F;
    if (u < KK * F) {  // WF (fragment-major for gemm_full)
        int j = u & 7, lane = (u >> 3) & 63, tt = (u >> 9) & 3, st = u >> 11;
        int col = tt * 16 + (lane & 15);
        int kk = st * 32 + ((lane >> 4) << 3) + j;
        WF[u] = f2bf(W[(size_t)kk * F + col]);
    }
}

// ---------- prop_v8: half-wave edge pairing ----------
// Each half-wave (32 lanes x uint = 2 bf16 features/lane) gathers a DIFFERENT
// edge's 128B row -> one vmem instruction covers 2 edges (issue count halved,
// same bytes, same 8 lines in flight). Halves take alternating int4 groups of
// the padded edge list; combine via shfl_xor(32). bf16-only state.

__global__ __launch_bounds__(256) void prop_v8(const ushort* __restrict__ Gsrc,
                                               const ushort* __restrict__ Gm2,
                                               ushort* __restrict__ Gout,
                                               const int* __restrict__ rp,
                                               const int* __restrict__ ce,
                                               const float* __restrict__ dinv,
                                               const int* __restrict__ deg,
                                               int Nv, int first) {
    __shared__ __align__(16) uint ush[PR_ROWS][32];  // 2 bf16 packed per uint
    int wave = threadIdx.x >> 6, lane = threadIdx.x & 63;
    int hl = lane >> 5, l31 = lane & 31;
    int rbase = blockIdx.x * PR_ROWS + wave * 4;

    if (blockIdx.x == 0 && threadIdx.x < 8)  // zero sentinel row of Gout
        ((uint4*)(Gout + (size_t)Nv * F))[threadIdx.x] = make_uint4(0, 0, 0, 0);

    for (int r = 0; r < 4; r++) {
        int i = rbase + r;
        bool act = i < Nv;
        int ii = act ? i : 0;
        float dr = dinv[ii];
        int dg = deg[ii];
        float sr = dg > 0 ? sqrtf((float)dg) : 1.f;   // 1/sinv
        uint tm2p = first ? 0u
                          : *(const uint*)(Gm2 + (size_t)ii * F + l31 * 2);  // prefetch
        int s = rp[ii], e = rp[ii + 1];
        float f0a = 0.f, f1a = 0.f, f0b = 0.f, f1b = 0.f;
        float f0c = 0.f, f1c = 0.f, f0d = 0.f, f1d = 0.f;
        for (int p = s + hl * 4; p < e; p += 8) {  // alternating int4 groups
            int4 q = *(const int4*)(ce + p);
            uint va = *(const uint*)(Gsrc + (size_t)q.x * F + l31 * 2);
            uint vb = *(const uint*)(Gsrc + (size_t)q.y * F + l31 * 2);
            uint vc = *(const uint*)(Gsrc + (size_t)q.z * F + l31 * 2);
            uint vd = *(const uint*)(Gsrc + (size_t)q.w * F + l31 * 2);
            f0a += bf2f((ushort)va); f1a += bf2f((ushort)(va >> 16));
            f0b += bf2f((ushort)vb); f1b += bf2f((ushort)(vb >> 16));
            f0c += bf2f((ushort)vc); f1c += bf2f((ushort)(vc >> 16));
            f0d += bf2f((ushort)vd); f1d += bf2f((ushort)(vd >> 16));
        }
        float f0 = (f0a + f0b) + (f0c + f0d);
        float f1 = (f1a + f1b) + (f1c + f1d);
        f0 += __shfl_xor(f0, 32, 64);  // combine the two halves
        f1 += __shfl_xor(f1, 32, 64);
        float raw0 = -dr * f0, raw1 = -dr * f1;
        float tk0 = first ? raw0 : fmaf(2.f, raw0, -sr * bf2f((ushort)tm2p));
        float tk1 = first ? raw1 : fmaf(2.f, raw1, -sr * bf2f((ushort)(tm2p >> 16)));
        float sv = dr > 0.f ? dr : 1.f;
        uint pk = (uint)f2bf(sv * tk0) | ((uint)f2bf(sv * tk1) << 16);
        if (hl == 0) ush[wave * 4 + r][l31] = pk;
    }
    __syncthreads();
    int t = threadIdx.x;
    if (t < 128) {  // 16 rows * 128B = 128 uint4 contiguous full lines
        int row = t >> 3;
        if (blockIdx.x * PR_ROWS + row < Nv)
            ((uint4*)Gout)[(size_t)blockIdx.x * 128 + t] = ((const uint4*)ush)[t];
    }
}

// ---------- gemm_full: out = ELU(LN(sr * sum_k T~_k @ W_k + bias)) ----------

__global__ __launch_bounds__(256) void gemm_full(
    const ushort* __restrict__ g0, const ushort* __restrict__ g1,
    const ushort* __restrict__ g2, const ushort* __restrict__ g3,
    const ushort* __restrict__ g4, const ushort* __restrict__ g5,
    const ushort* __restrict__ g6, const ushort* __restrict__ g7,
    const ushort* __restrict__ WF,
    float* __restrict__ out, const float* __restrict__ bias,
    const float* __restrict__ lnw, const float* __restrict__ lnb,
    const int* __restrict__ deg, int Nv) {
    __shared__ __align__(16) ushort A_lds[4 * 64 * 64];  // 32 KB
    uint4* Au4 = (uint4*)A_lds;
    int wave = threadIdx.x >> 6, lane = threadIdx.x & 63;
    int rbase64 = blockIdx.x * 64;
    if (rbase64 >= Nv) return;
    int rbase = rbase64 + wave * 16;
    int r15 = lane & 15, kg = lane >> 4;

    f32x4 acc[4];
#pragma unroll
    for (int t = 0; t < 4; t++) acc[t] = (f32x4){0.f, 0.f, 0.f, 0.f};

#define STAGE4(pA, pB, pC, pD)                                                  \
    {                                                                           \
        const ushort* ps_[4] = {pA, pB, pC, pD};                                \
        _Pragma("unroll")                                                       \
        for (int s4_ = 0; s4_ < 4; s4_++) {                                     \
            const ushort* A_ = ps_[s4_];                                        \
            _Pragma("unroll")                                                   \
            for (int it_ = 0; it_ < 2; it_++) {                                 \
                int lin_ = it_ * 256 + threadIdx.x;                             \
                int r_ = lin_ >> 3, c_ = lin_ & 7;                              \
                int grow_ = rbase64 + r_;                                       \
                if (grow_ > Nv) grow_ = Nv; /* sentinel zeros */                \
                uint4 v_ = *(const uint4*)(A_ + (size_t)grow_ * F + c_ * 8);    \
                Au4[(s4_ * 64 + r_) * 8 + (c_ ^ (r_ & 7))] = v_;                \
            }                                                                   \
        }                                                                       \
    }

    STAGE4(g0, g1, g2, g3);
    __syncthreads();
#pragma unroll
    for (int st8 = 0; st8 < 8; st8++) {        // slices 0..3
        int s4 = st8 >> 1, half = st8 & 1;
        int cidx = (half * 4 + kg) ^ (r15 & 7);
        short8 a = *(const short8*)&A_lds[((s4 * 64 + wave * 16 + r15) * 8 + cidx) * 8];
#pragma unroll
        for (int t = 0; t < 4; t++) {
            short8 b = *(const short8*)(WF + (((size_t)st8 * 4 + t) * 64 + lane) * 8);
            acc[t] = __builtin_amdgcn_mfma_f32_16x16x32_bf16(a, b, acc[t], 0, 0, 0);
        }
    }
    __syncthreads();
    STAGE4(g4, g5, g6, g7);
    __syncthreads();
#pragma unroll
    for (int st8 = 0; st8 < 8; st8++) {        // slices 4..7
        int s4 = st8 >> 1, half = st8 & 1;
        int cidx = (half * 4 + kg) ^ (r15 & 7);
        short8 a = *(const short8*)&A_lds[((s4 * 64 + wave * 16 + r15) * 8 + cidx) * 8];
#pragma unroll
        for (int t = 0; t < 4; t++) {
            short8 b = *(const short8*)(WF + (((size_t)(st8 + 8) * 4 + t) * 64 + lane) * 8);
            acc[t] = __builtin_amdgcn_mfma_f32_16x16x32_bf16(a, b, acc[t], 0, 0, 0);
        }
    }
#undef STAGE4

    float bc[4], wc[4], gc[4];
#pragma unroll
    for (int t = 0; t < 4; t++) {
        int col = t * 16 + r15;
        bc[t] = bias[col]; wc[t] = lnw[col]; gc[t] = lnb[col];
    }
#pragma unroll
    for (int j = 0; j < 4; j++) {
        int row = rbase + kg * 4 + j;
        int rr = row < Nv ? row : Nv - 1;  // whole 16-lane group uniform
        int dg = deg[rr];
        float sr = dg > 0 ? sqrtf((float)dg) : 1.f;  // undo sinv row scale
        float v[4];
        float s = 0.f;
#pragma unroll
        for (int t = 0; t < 4; t++) {
            v[t] = acc[t][j] * sr + bc[t];
            s += v[t];
        }
        s += __shfl_xor(s, 1, 64); s += __shfl_xor(s, 2, 64);
        s += __shfl_xor(s, 4, 64); s += __shfl_xor(s, 8, 64);
        float mu = s * (1.f / F);
        float q = 0.f;
#pragma unroll
        for (int t = 0; t < 4; t++) { float d = v[t] - mu; q += d * d; }
        q += __shfl_xor(q, 1, 64); q += __shfl_xor(q, 2, 64);
        q += __shfl_xor(q, 4, 64); q += __shfl_xor(q, 8, 64);
        float inv = rsqrtf(q * (1.f / F) + 1e-5f);
        if (row < Nv) {
#pragma unroll
            for (int t = 0; t < 4; t++) {
                int col = t * 16 + r15;
                float y = (v[t] - mu) * inv * wc[t] + gc[t];
                out[(size_t)row * F + col] = y > 0.f ? y : expm1f(y);
            }
        }
    }
}

// ---------- pair-GEMM fallback (only if workspace too small for 8 slices) ----------

template <int NSL, int FIRST, int LAST>
__global__ __launch_bounds__(256) void gemm_all(
    const ushort* __restrict__ g0, const ushort* __restrict__ g1,
    const ushort* __restrict__ g2, const ushort* __restrict__ g3,
    const ushort* __restrict__ g4, const ushort* __restrict__ g5,
    const ushort* __restrict__ g6, const ushort* __restrict__ g7,
    const ushort* __restrict__ WbT, int kkbase, int KK,
    float* __restrict__ out, const float* __restrict__ bias,
    const float* __restrict__ lnw, const float* __restrict__ lnb,
    const int* __restrict__ deg, int Nv) {
    const ushort* gs[8] = {g0, g1, g2, g3, g4, g5, g6, g7};
    int wave = threadIdx.x >> 6, lane = threadIdx.x & 63;
    int rbase = (blockIdx.x * 4 + wave) * 16;
    if (rbase >= Nv) return;
    int r15 = lane & 15, kg = lane >> 4;
    int arow = rbase + r15;
    if (arow >= Nv) arow = Nv - 1;

    f32x4 acc[4];
#pragma unroll
    for (int t = 0; t < 4; t++) acc[t] = (f32x4){0.f, 0.f, 0.f, 0.f};

#pragma unroll
    for (int st = 0; st < 2 * NSL; st++) {
        const ushort* A = gs[st >> 1];
        short8 a = *(const short8*)(A + (size_t)arow * F + (st & 1) * 32 + kg * 8);
#pragma unroll
        for (int t = 0; t < 4; t++) {
            int col = t * 16 + r15;
            short8 b = *(const short8*)(WbT + (size_t)col * KK + kkbase + st * 32 + kg * 8);
            acc[t] = __builtin_amdgcn_mfma_f32_16x16x32_bf16(a, b, acc[t], 0, 0, 0);
        }
    }

    if (!LAST) {
#pragma unroll
        for (int t = 0; t < 4; t++) {
            int col = t * 16 + r15;
#pragma unroll
            for (int j = 0; j < 4; j++) {
                int row = rbase + kg * 4 + j;
                if (row < Nv) {
                    size_t idx = (size_t)row * F + col;
                    out[idx] = FIRST ? acc[t][j] : out[idx] + acc[t][j];
                }
            }
        }
    } else {
        float bc[4], wc[4], gc[4];
#pragma unroll
        for (int t = 0; t < 4; t++) {
            int col = t * 16 + r15;
            bc[t] = bias[col]; wc[t] = lnw[col]; gc[t] = lnb[col];
        }
#pragma unroll
        for (int j = 0; j < 4; j++) {
            int row = rbase + kg * 4 + j;
            int rr = row < Nv ? row : Nv - 1;
            int dg = deg[rr];
            float sr = dg > 0 ? sqrtf((float)dg) : 1.f;
            float v[4];
            float s = 0.f;
#pragma unroll
            for (int t = 0; t < 4; t++) {
                int col = t * 16 + r15;
                float a_ = acc[t][j];
                if (!FIRST) a_ += out[(size_t)rr * F + col];
                v[t] = a_ * sr + bc[t];
                s += v[t];
            }
            s += __shfl_xor(s, 1, 64); s += __shfl_xor(s, 2, 64);
            s += __shfl_xor(s, 4, 64); s += __shfl_xor(s, 8, 64);
            float mu = s * (1.f / F);
            float q = 0.f;
#pragma unroll
            for (int t = 0; t < 4; t++) { float d = v[t] - mu; q += d * d; }
            q += __shfl_xor(q, 1, 64); q += __shfl_xor(q, 2, 64);
            q += __shfl_xor(q, 4, 64); q += __shfl_xor(q, 8, 64);
            float inv = rsqrtf(q * (1.f / F) + 1e-5f);
            if (row < Nv) {
#pragma unroll
                for (int t = 0; t < 4; t++) {
                    int col = t * 16 + r15;
                    float y = (v[t] - mu) * inv * wc[t] + gc[t];
                    out[(size_t)row * F + col] = y > 0.f ? y : expm1f(y);
                }
            }
        }
    }
}

// ---------- host ----------

extern "C" void kernel_launch(void* const* d_in, const int* in_sizes, int n_in,
                              void* d_out, int out_size, void* d_ws, size_t ws_size,
                              hipStream_t stream) {
    (void)n_in; (void)out_size;
    const float* x    = (const float*)d_in[0];
    const int*   ei   = (const int*)d_in[1];
    const float* W    = (const float*)d_in[2];
    const float* bias = (const float*)d_in[3];
    const float* lnw  = (const float*)d_in[4];
    const float* lnb  = (const float*)d_in[5];
    float* out = (float*)d_out;

    int Nv = in_sizes[0] / F;
    int E  = in_sizes[1] / 2;
    int K  = in_sizes[2] / (F * F);  // 8
    int KK = K * F;
    float invg = 8.0f / (float)Nv;

    char* base = (char*)d_ws;
    size_t off = 0;
    auto alloc = [&](size_t b) -> void* {
        void* p = base + off;
        off += (b + 255) & ~(size_t)255;
        return p;
    };
    int*    degfill = (int*)alloc((size_t)2 * Nv * 4);  // deg | fill, one memset
    int*    deg  = degfill;
    int*    fill = degfill + Nv;
    int*    rp   = (int*)alloc(((size_t)Nv + 1) * 4);
    int     nb   = (Nv + 1023) / 1024;
    int*    bsum = (int*)alloc((size_t)nb * 4);
    float*  dinv = (float*)alloc((size_t)Nv * 4);
    int*    ce   = (int*)alloc(((size_t)E + 8 * Nv) * 4);  // padded CSR columns
    ushort* WbT  = (ushort*)alloc((size_t)KK * F * 2);
    ushort* WF   = (ushort*)alloc((size_t)KK * F * 2);
    size_t fixed = off;

    size_t gbytes = ((size_t)Nv + 1) * F * 2;  // one bf16 slice incl. sentinel row
    size_t galign = (gbytes + 255) & ~(size_t)255;
    int full = (K == 8 && fixed + 8 * galign <= ws_size) ? 1 : 0;
    int nG = full ? 8 : 3;
    ushort* G[8];
    for (int i = 0; i < nG; i++) G[i] = (ushort*)alloc(gbytes);
    if (off > ws_size) return;

    hipMemsetAsync(degfill, 0, (size_t)2 * Nv * 4, stream);

    int gE = (E + 255) / 256, gN = (Nv + 255) / 256;
    deg_kernel<<<8 * gE, 256, 0, stream>>>(ei, E, deg, invg);
    scan1_kernel<<<nb, 256, 0, stream>>>(deg, rp, bsum, Nv);
    scan2_kernel<<<1, 256, 0, stream>>>(bsum, nb);
    scan3_kernel<<<gN, 256, 0, stream>>>(rp, bsum, deg, dinv, Nv);
    scatter_kernel<<<8 * gE, 256, 0, stream>>>(ei, E, rp, fill, dinv, deg, ce, Nv, invg);

    int n4 = (Nv * F) / 4;
    int initN = n4 + 2 * KK * F;
    init_kernel<<<(initN + 255) / 256, 256, 0, stream>>>((const float4*)x, (ushort4*)G[0],
                                                         dinv, W, WbT, WF, n4, KK, Nv);

    int gP = (Nv + PR_ROWS - 1) / PR_ROWS;
    int gG = (Nv + 63) / 64;

    for (int k = 1; k < K; k++) {
        const ushort* gsrc = full ? G[k - 1] : G[(k - 1) % 3];
        const ushort* gm2  = (k < 2) ? (const ushort*)nullptr
                                     : (full ? G[k - 2] : G[(k - 2) % 3]);
        ushort*       gdst = full ? G[k] : G[k % 3];
        prop_v8<<<gP, 256, 0, stream>>>(gsrc, gm2, gdst, rp, ce, dinv, deg,
                                        Nv, k == 1 ? 1 : 0);
        if (!full && (k & 1)) {  // pair rotation fallback
            int p = k >> 1;
            const ushort* a0 = G[(2 * p) % 3];
            const ushort* a1 = G[(2 * p + 1) % 3];
            if (p == 0)
                gemm_all<2, 1, 0><<<gG, 256, 0, stream>>>(a0, a1, 0, 0, 0, 0, 0, 0,
                    WbT, p * 128, KK, out, bias, lnw, lnb, deg, Nv);
            else if (k < K - 1)
                gemm_all<2, 0, 0><<<gG, 256, 0, stream>>>(a0, a1, 0, 0, 0, 0, 0, 0,
                    WbT, p * 128, KK, out, bias, lnw, lnb, deg, Nv);
            else
                gemm_all<2, 0, 1><<<gG, 256, 0, stream>>>(a0, a1, 0, 0, 0, 0, 0, 0,
                    WbT, p * 128, KK, out, bias, lnw, lnb, deg, Nv);
        }
    }
    if (full)
        gemm_full<<<gG, 256, 0, stream>>>(G[0], G[1], G[2], G[3],
                                          G[4], G[5], G[6], G[7],
                                          WF, out, bias, lnw, lnb, deg, Nv);
}